// Round 2
// baseline (312.073 us; speedup 1.0000x reference)
//
#include <hip/hip_runtime.h>

// B=4, T=2048, C=1024, H=16, D=64. Device buffers f32 (mask int32).
// R11 = R10 with the attn P-transpose eliminated (swapped-QK^T, T12-style):
//   - S^T = mfma(K, Q) with key->A-row mapping rowmap_n(i)=koff[n]+(i>>2)*8+(i&3),
//     koff={0,4,32,36}. Each lane then holds exactly the 16 P values its PV
//     A-fragment needs (keys quad*8+[0..7] and 32+quad*8+[0..7]) -> P never
//     touches LDS. Plds deleted (8 ds_write_b64 + 4 ds_read_b128 + ~40 VALU
//     addressing per tile-thread gone).
//   - P packed with hardware v_cvt_pk_bf16_f32 (16 instr vs 48 bit-trick ops).
//   - mask bias precomputed once into bias_lds[2048] (f32, 8KB): per tile 4
//     broadcast ds_read_b128, zero cndmask, no per-tile mask vmem load.
//   - Ks swizzle now sigma(row)=((row>>3)&1)<<2|(row&3): QK^T A-frag reads are
//     conflict-free within each 8-lane group (staging pre-swizzle matches).
//   - lsum: 2 scalars/lane, epilogue reduce = 2 shfl_xor (16,32) + bcast.
//   - LDS 51200 -> 40960 -> 4 blocks/CU (occupancy 2-3 -> 4 blocks).
// Keeps: R10 double-buffered single-barrier pipeline, prefetch-first, raw
// s_barrier + trailing vmcnt(0), setprio around MFMA clusters, v_exp_f32
// softmax, V^T [d][key] tile sigma=row&7. GEMM path frozen from R6.

#define TT 2048
#define CC 1024
#define HH 16
#define DD 64
#define BB 4

typedef unsigned short u16;
typedef unsigned int u32;
typedef __attribute__((ext_vector_type(8))) short bf16x8;
typedef __attribute__((ext_vector_type(4))) float f32x4;
typedef __attribute__((ext_vector_type(4))) u32 u32x4;

#if __has_builtin(__builtin_amdgcn_exp2f)
#define EXP2(x) __builtin_amdgcn_exp2f(x)
#else
#define EXP2(x) __expf((x) * 0.6931471805599453f)
#endif

__device__ __forceinline__ u16 f2bf(float f) {
    u32 u = __builtin_bit_cast(u32, f);
    u += 0x7FFFu + ((u >> 16) & 1u);
    return (u16)(u >> 16);
}
__device__ __forceinline__ u32 pk2(float a, float b) {
    u32 ua = __builtin_bit_cast(u32, a); ua += 0x7FFFu + ((ua >> 16) & 1u);
    u32 ub = __builtin_bit_cast(u32, b); ub += 0x7FFFu + ((ub >> 16) & 1u);
    return __builtin_amdgcn_perm(ub, ua, 0x07060302);  // {hi16(ub), hi16(ua)}
}
// hardware packed f32->bf16: dst.lo16 = bf16(lo), dst.hi16 = bf16(hi)
__device__ __forceinline__ u32 cvtpk(float lo, float hi) {
    u32 r;
    asm("v_cvt_pk_bf16_f32 %0, %1, %2" : "=v"(r) : "v"(lo), "v"(hi));
    return r;
}

#define GLDS(g, l) __builtin_amdgcn_global_load_lds( \
    (const __attribute__((address_space(1))) void*)(g), \
    (__attribute__((address_space(3))) void*)(l), 16, 0, 0)

// ---------------------------------------------------------------------------
__global__ __launch_bounds__(256) void wcvt(const float* __restrict__ s,
                                            u16* __restrict__ d, int n8) {
    const int i = blockIdx.x * 256 + threadIdx.x;
    if (i < n8) {
        const float4 f0 = ((const float4*)s)[2 * i];
        const float4 f1 = ((const float4*)s)[2 * i + 1];
        uint4 w;
        w.x = pk2(f0.x, f0.y); w.y = pk2(f0.z, f0.w);
        w.z = pk2(f1.x, f1.y); w.w = pk2(f1.z, f1.w);
        ((uint4*)d)[i] = w;
    }
}

__global__ __launch_bounds__(256) void wcvt3(const float* __restrict__ s0,
                                             const float* __restrict__ s1,
                                             const float* __restrict__ s2,
                                             u16* __restrict__ d0,
                                             u16* __restrict__ d1,
                                             u16* __restrict__ d2, int n8) {
    const int which = blockIdx.y;
    const float* s = (which == 0) ? s0 : (which == 1) ? s1 : s2;
    u16* d = (which == 0) ? d0 : (which == 1) ? d1 : d2;
    const int i = blockIdx.x * 256 + threadIdx.x;
    if (i < n8) {
        const float4 f0 = ((const float4*)s)[2 * i];
        const float4 f1 = ((const float4*)s)[2 * i + 1];
        uint4 w;
        w.x = pk2(f0.x, f0.y); w.y = pk2(f0.z, f0.w);
        w.z = pk2(f1.x, f1.y); w.w = pk2(f1.z, f1.w);
        ((uint4*)d)[i] = w;
    }
}

// ---------------------------------------------------------------------------
// GEMM out = A[8192,1024] @ W[N,1024]^T + bias. All-bf16, GLDS staging,
// 128x128 tile, BK=64, XOR chunk swizzle. PROJ=1: f32 out. PROJ=0: fused
// QKV (N=3072): Q rowmajor | K rowmajor | V^T [B,H,D,T].
// ---------------------------------------------------------------------------
template <int PROJ>
__global__ __launch_bounds__(256) void gemmX(const u16* __restrict__ A,
                                             const u16* __restrict__ Wb,
                                             const float* __restrict__ b0,
                                             const float* __restrict__ b1,
                                             const float* __restrict__ b2,
                                             void* __restrict__ out0,
                                             void* __restrict__ out1,
                                             void* __restrict__ out2) {
    __shared__ u16 As[128 * 64];
    __shared__ u16 Bs[128 * 64];

    const int tid  = threadIdx.x;
    const int wave = tid >> 6, lane = tid & 63;
    const int quad = lane >> 4, l16 = lane & 15;
    const int bm = blockIdx.y * 128, bn = blockIdx.x * 128;
    const int wm = (wave >> 1) * 64, wn = (wave & 1) * 64;
    const int K = CC;

    f32x4 acc[4][4] = {};

    for (int k0 = 0; k0 < K; k0 += 64) {
#pragma unroll
        for (int rr = 0; rr < 4; rr++) {
            const int c = rr * 256 + tid;
            const int row = c >> 3;
            const int cs = ((c & 7) ^ (row & 7)) * 8;
            GLDS(&Wb[(size_t)(bn + row) * K + k0 + cs], &Bs[c * 8]);
        }
#pragma unroll
        for (int rr = 0; rr < 4; rr++) {
            const int c = rr * 256 + tid;
            const int row = c >> 3;
            const int cs = ((c & 7) ^ (row & 7)) * 8;
            GLDS(&A[(size_t)(bm + row) * K + k0 + cs], &As[c * 8]);
        }
        __syncthreads();

#pragma unroll
        for (int ks = 0; ks < 2; ks++) {
            bf16x8 af[4], bfr[4];
#pragma unroll
            for (int i = 0; i < 4; i++) {
                const int row = wm + i * 16 + l16;
                const int s8 = (ks * 4 + quad) ^ (row & 7);
                af[i] = *(bf16x8*)&As[row * 64 + s8 * 8];
            }
#pragma unroll
            for (int j = 0; j < 4; j++) {
                const int row = wn + j * 16 + l16;
                const int s8 = (ks * 4 + quad) ^ (row & 7);
                bfr[j] = *(bf16x8*)&Bs[row * 64 + s8 * 8];
            }
#pragma unroll
            for (int i = 0; i < 4; i++)
#pragma unroll
                for (int j = 0; j < 4; j++)
                    acc[i][j] = __builtin_amdgcn_mfma_f32_16x16x32_bf16(af[i], bfr[j], acc[i][j], 0, 0, 0);
        }
        __syncthreads();
    }

    if (PROJ) {
        float* out = (float*)out0;
#pragma unroll
        for (int j = 0; j < 4; j++) {
            const int col = bn + wn + j * 16 + l16;
            const float bv = b0[col];
#pragma unroll
            for (int i = 0; i < 4; i++) {
                const int row0 = bm + wm + i * 16 + quad * 4;
#pragma unroll
                for (int r = 0; r < 4; r++)
                    out[(size_t)(row0 + r) * CC + col] = acc[i][j][r] + bv;
            }
        }
    } else {
        const int mid = bn >> 10;   // 0=Q,1=K,2=V (block-uniform)
        const float* bias = (mid == 0) ? b0 : (mid == 1) ? b1 : b2;
#pragma unroll
        for (int j = 0; j < 4; j++) {
            const int col  = bn + wn + j * 16 + l16;
            const int colL = col & (CC - 1);
            const float bv = bias[colL];
#pragma unroll
            for (int i = 0; i < 4; i++) {
                const int row0 = bm + wm + i * 16 + quad * 4;
                if (mid < 2) {
                    u16* out = (u16*)(mid ? out1 : out0);
#pragma unroll
                    for (int r = 0; r < 4; r++)
                        out[(size_t)(row0 + r) * CC + colL] = f2bf(acc[i][j][r] + bv);
                } else {
                    const int hh = colL >> 6, dch = colL & 63;
                    const int bb = row0 >> 11, t0 = row0 & (TT - 1);
                    const size_t idx = (((size_t)bb * HH + hh) * DD + dch) * TT + t0;
                    uint2 w;
                    w.x = pk2(acc[i][j][0] + bv, acc[i][j][1] + bv);
                    w.y = pk2(acc[i][j][2] + bv, acc[i][j][3] + bv);
                    *(uint2*)&((u16*)out2)[idx] = w;
                }
            }
        }
    }
}

// ---------------------------------------------------------------------------
// Flash attention. Block = (qt,h,b): 128 q-rows, 4 waves x 32 rows (2 m-frags).
// Swapped QK^T: S^T = mfma(K as A, Q as B). Key->A-row map per frag n:
// rowmap_n(i) = koff[n] + (i>>2)*8 + (i&3), koff={0,4,32,36}. C-layout
// (col=l16=q, row=quad*4+r=key-slot) then gives lane (quad,l16) exactly keys
// {quad*8+0..7} u {32+quad*8+0..7} for q=m*16+l16 -> the PV A-fragment,
// in-register, after cvt_pk packing. No P LDS round-trip.
// Ks [key][dim] sigma=((row>>3)&1)<<2|(row&3); Vs [d][key] sigma=row&7.
// Double-buffered GLDS, single raw barrier per tile, prefetch-first.
// No online max (|s/8| bounded; masked -> -1e38 bias -> p=0).
// ---------------------------------------------------------------------------
__global__ __launch_bounds__(256) void attn(const u16* __restrict__ Q,
                                            const u16* __restrict__ Kb,
                                            const u16* __restrict__ Vt,
                                            const int* __restrict__ mask,
                                            u16* __restrict__ Y) {
    const int b = blockIdx.z, h = blockIdx.y, qt = blockIdx.x;
    const int tid  = threadIdx.x;
    const int wave = tid >> 6, lane = tid & 63;
    const int quad = lane >> 4, l16 = lane & 15;
    const int qrow0 = qt * 128 + wave * 32;

    __shared__ u16 Ks[2][64 * 64];              // [key][dim]
    __shared__ u16 Vs[2][64 * 64];              // [d][key]
    __shared__ __align__(16) float bias_lds[TT];  // 0 or -1e38 per key

    const size_t qb = ((size_t)b * TT + qrow0) * CC + h * DD;

    bf16x8 qf[2][2];
#pragma unroll
    for (int m = 0; m < 2; m++)
#pragma unroll
        for (int ks = 0; ks < 2; ks++)
            qf[m][ks] = *(const bf16x8*)&Q[qb + (size_t)(m * 16 + l16) * CC + ks * 32 + quad * 8];

    // one-time mask -> bias table (8 keys per thread)
    {
        const int i = tid * 8;
        const int4 m0 = *(const int4*)&mask[b * TT + i];
        const int4 m1 = *(const int4*)&mask[b * TT + i + 4];
        bias_lds[i + 0] = m0.x ? 0.f : -1e38f;
        bias_lds[i + 1] = m0.y ? 0.f : -1e38f;
        bias_lds[i + 2] = m0.z ? 0.f : -1e38f;
        bias_lds[i + 3] = m0.w ? 0.f : -1e38f;
        bias_lds[i + 4] = m1.x ? 0.f : -1e38f;
        bias_lds[i + 5] = m1.y ? 0.f : -1e38f;
        bias_lds[i + 6] = m1.z ? 0.f : -1e38f;
        bias_lds[i + 7] = m1.w ? 0.f : -1e38f;
    }

    // staging: slot c -> row=c>>3, pos=c&7; fetch global chunk pos^sigma(row)
    const int c0 = tid, c1 = tid + 256;
    const int r0 = c0 >> 3, r1 = c1 >> 3;
    const int kp0 = (c0 & 7) ^ ((((r0 >> 3) & 1) << 2) | (r0 & 3));
    const int kp1 = (c1 & 7) ^ ((((r1 >> 3) & 1) << 2) | (r1 & 3));
    const int vp0 = (c0 & 7) ^ (r0 & 7), vp1 = (c1 & 7) ^ (r1 & 7);
    const u16* kgp = Kb + ((size_t)b * TT) * CC + h * DD;
    const u16* vgp = Vt + ((size_t)(b * HH + h) * DD) * TT;

    // QK^T A-frag read geometry (same sigma for all koff)
    const int rowA = ((l16 >> 2) << 3) | (l16 & 3);
    const int s0k  = (((l16 >> 2) & 1) << 2) | (l16 & 3);

    f32x4 o[2][4] = {};
    float lsum[2] = {};
    const float SC = 0.18033688011112042f;   // 0.125 * log2(e)

    // prologue: stage tile 0 into buffer 0; drain vm (stage) + lgkm (bias)
    GLDS(&kgp[(size_t)r0 * CC + kp0 * 8], &Ks[0][c0 * 8]);
    GLDS(&kgp[(size_t)r1 * CC + kp1 * 8], &Ks[0][c1 * 8]);
    GLDS(&vgp[(size_t)r0 * TT + vp0 * 8], &Vs[0][c0 * 8]);
    GLDS(&vgp[(size_t)r1 * TT + vp1 * 8], &Vs[0][c1 * 8]);
    asm volatile("s_waitcnt vmcnt(0) lgkmcnt(0)" ::: "memory");
    __builtin_amdgcn_s_barrier();
    __builtin_amdgcn_sched_barrier(0);

#pragma unroll 1
    for (int kt = 0; kt < TT; kt += 64) {
        const int cur = (kt >> 6) & 1;
        const u16* Kc = &Ks[cur][0];
        const u16* Vc = &Vs[cur][0];

        // prefetch tile t+1 into the other buffer; in flight across compute
        if (kt + 64 < TT) {
            const int nxt = cur ^ 1;
            GLDS(&kgp[(size_t)(kt + 64 + r0) * CC + kp0 * 8], &Ks[nxt][c0 * 8]);
            GLDS(&kgp[(size_t)(kt + 64 + r1) * CC + kp1 * 8], &Ks[nxt][c1 * 8]);
            GLDS(&vgp[(size_t)r0 * TT + kt + 64 + vp0 * 8], &Vs[nxt][c0 * 8]);
            GLDS(&vgp[(size_t)r1 * TT + kt + 64 + vp1 * 8], &Vs[nxt][c1 * 8]);
        }

        // bias for this tile's 16 lane-held keys (broadcast LDS reads)
        const f32x4 bA = *(const f32x4*)&bias_lds[kt + quad * 8];
        const f32x4 bB = *(const f32x4*)&bias_lds[kt + quad * 8 + 4];
        const f32x4 bC = *(const f32x4*)&bias_lds[kt + 32 + quad * 8];
        const f32x4 bD = *(const f32x4*)&bias_lds[kt + 32 + quad * 8 + 4];

        // ---- S^T = K Q^T : A=K (rowmap), B=Q ----
        f32x4 s2[2][4] = {};
        __builtin_amdgcn_s_setprio(1);
#pragma unroll
        for (int n = 0; n < 4; n++) {
            const int rowK = rowA + (n & 1) * 4 + (n >> 1) * 32;
#pragma unroll
            for (int ks = 0; ks < 2; ks++) {
                const int pos = ((ks << 2) + quad) ^ s0k;
                const bf16x8 kf = *(const bf16x8*)&Kc[rowK * 64 + pos * 8];
#pragma unroll
                for (int m = 0; m < 2; m++)
                    s2[m][n] = __builtin_amdgcn_mfma_f32_16x16x32_bf16(kf, qf[m][ks], s2[m][n], 0, 0, 0);
            }
        }
        __builtin_amdgcn_s_setprio(0);

        // ---- softmax in-register; pack straight into PV A-frag words ----
        // s2[m][n][r] = S[q=m*16+l16][key = koff[n] + quad*8 + r]
        u32 pkk[2][8];
#pragma unroll
        for (int m = 0; m < 2; m++) {
            float ls = 0.f;
#pragma unroll
            for (int n = 0; n < 4; n++) {
                const f32x4 bv = (n == 0) ? bA : (n == 1) ? bB : (n == 2) ? bC : bD;
                const float p0 = EXP2(fmaf(s2[m][n][0], SC, bv[0]));
                const float p1 = EXP2(fmaf(s2[m][n][1], SC, bv[1]));
                const float p2 = EXP2(fmaf(s2[m][n][2], SC, bv[2]));
                const float p3 = EXP2(fmaf(s2[m][n][3], SC, bv[3]));
                ls += (p0 + p1) + (p2 + p3);
                pkk[m][2 * n]     = cvtpk(p0, p1);
                pkk[m][2 * n + 1] = cvtpk(p2, p3);
            }
            lsum[m] += ls;
        }

        // ---- O += P V (P already in-register as A-frags) ----
        __builtin_amdgcn_s_setprio(1);
#pragma unroll
        for (int ks = 0; ks < 2; ks++) {
            bf16x8 pf[2];
#pragma unroll
            for (int m = 0; m < 2; m++) {
                const u32x4 t = { pkk[m][4 * ks + 0], pkk[m][4 * ks + 1],
                                  pkk[m][4 * ks + 2], pkk[m][4 * ks + 3] };
                pf[m] = __builtin_bit_cast(bf16x8, t);
            }
#pragma unroll
            for (int dt = 0; dt < 4; dt++) {
                const int vrow = dt * 16 + l16;
                const int pos = ((ks << 2) + quad) ^ (vrow & 7);
                const bf16x8 vf = *(const bf16x8*)&Vc[vrow * 64 + pos * 8];
#pragma unroll
                for (int m = 0; m < 2; m++)
                    o[m][dt] = __builtin_amdgcn_mfma_f32_16x16x32_bf16(pf[m], vf, o[m][dt], 0, 0, 0);
            }
        }
        __builtin_amdgcn_s_setprio(0);

        // drain prefetch (had the whole compute phase to land), then sync.
        asm volatile("s_waitcnt vmcnt(0)" ::: "memory");
        __builtin_amdgcn_sched_barrier(0);
        __builtin_amdgcn_s_barrier();
    }

    // lsum[m] is a partial over this lane's 16 keys; full sum lives across
    // the 4 quads sharing l16 -> xor-16 + xor-32.
#pragma unroll
    for (int m = 0; m < 2; m++) {
        lsum[m] += __shfl_xor(lsum[m], 16, 64);
        lsum[m] += __shfl_xor(lsum[m], 32, 64);
    }

#pragma unroll
    for (int m = 0; m < 2; m++) {
        float inv[4];
#pragma unroll
        for (int r = 0; r < 4; r++)
            inv[r] = 1.0f / __shfl(lsum[m], quad * 4 + r, 64);  // lane l16=quad*4+r
#pragma unroll
        for (int dt = 0; dt < 4; dt++)
#pragma unroll
            for (int r = 0; r < 4; r++)
                Y[qb + (size_t)(m * 16 + quad * 4 + r) * CC + dt * 16 + l16] = f2bf(o[m][dt][r] * inv[r]);
    }
}

// ---------------------------------------------------------------------------
extern "C" void kernel_launch(void* const* d_in, const int* in_sizes, int n_in,
                              void* d_out, int out_size, void* d_ws, size_t ws_size,
                              hipStream_t stream) {
    const float* x    = (const float*)d_in[0];
    const int*   mask = (const int*)d_in[1];
    const float* Wq   = (const float*)d_in[2];
    const float* bq   = (const float*)d_in[3];
    const float* Wk   = (const float*)d_in[4];
    const float* bk   = (const float*)d_in[5];
    const float* Wv   = (const float*)d_in[6];
    const float* bv   = (const float*)d_in[7];
    const float* Wp   = (const float*)d_in[8];
    const float* bp   = (const float*)d_in[9];

    u16* ws = (u16*)d_ws;
    const size_t sz = (size_t)BB * TT * CC;     // 8,388,608 elems
    u16* Qb   = ws;              // Q; attn writes O here
    u16* Kbuf = ws + sz;         // K; reused for bf16 Wp after attn
    u16* Vtb  = ws + 2 * sz;     // V^T [B,H,D,T]   (ws total 48 MiB)

    u16* xb   = (u16*)d_out;     // squatters in d_out (dead by proj GEMM)
    u16* Wq16 = xb + sz;
    u16* Wk16 = Wq16 + (size_t)CC * CC;
    u16* Wv16 = Wk16 + (size_t)CC * CC;

    const int W8 = CC * CC / 8;      // 131072
    wcvt<<<4096, 256, 0, stream>>>(x, xb, (int)(sz / 8));
    wcvt3<<<dim3(512, 3), 256, 0, stream>>>(Wq, Wk, Wv, Wq16, Wk16, Wv16, W8);

    gemmX<0><<<dim3(24, 64), 256, 0, stream>>>(xb, Wq16, bq, bk, bv, Qb, Kbuf, Vtb);

    attn<<<dim3(TT / 128, HH, BB), 256, 0, stream>>>(Qb, Kbuf, Vtb, mask, Qb);

    wcvt<<<512, 256, 0, stream>>>(Wp, Kbuf, W8);   // K dead after attn
    gemmX<1><<<dim3(8, 64), 256, 0, stream>>>(Qb, Kbuf, bp, nullptr, nullptr, d_out, nullptr, nullptr);
}

// Round 3
// 289.476 us; speedup vs baseline: 1.0781x; 1.0781x over previous
//
#include <hip/hip_runtime.h>

// B=4, T=2048, C=1024, H=16, D=64. Device buffers f32 (mask int32).
// R12 = R11 with attn occupancy/intensity changes:
//   - 512-thread blocks (8 waves), 256 q-rows per block. Same 64-key tile
//     serves 2x q-rows: staging 4 -> 2 GLDS/thread/tile, 512 blocks,
//     8 waves per barrier domain (mixed softmax/MFMA phases -> cross-wave
//     pipe overlap), LDS 40960 -> up to 4 blocks x 8 waves = 32 waves/CU.
//   - ks-split softmax/PV interleave: softmax(n=0,1) -> PV(ks=0) ->
//     softmax(n=2,3) -> PV(ks=1). Halves the serial VALU stretch before
//     the first PV MFMA; shrinks pkk register lifetime.
// Keeps: R11 swapped-QK^T in-register P (conflicts 6.3M->65K verified),
// cvt_pk packing, bias_lds table, Ks sigma=((row>>3)&1)<<2|(row&3),
// Vs sigma=row&7, double-buffered single-barrier pipeline, setprio,
// v_exp_f32 softmax. GEMM path frozen from R6.

#define TT 2048
#define CC 1024
#define HH 16
#define DD 64
#define BB 4

typedef unsigned short u16;
typedef unsigned int u32;
typedef __attribute__((ext_vector_type(8))) short bf16x8;
typedef __attribute__((ext_vector_type(4))) float f32x4;
typedef __attribute__((ext_vector_type(4))) u32 u32x4;

#if __has_builtin(__builtin_amdgcn_exp2f)
#define EXP2(x) __builtin_amdgcn_exp2f(x)
#else
#define EXP2(x) __expf((x) * 0.6931471805599453f)
#endif

__device__ __forceinline__ u16 f2bf(float f) {
    u32 u = __builtin_bit_cast(u32, f);
    u += 0x7FFFu + ((u >> 16) & 1u);
    return (u16)(u >> 16);
}
__device__ __forceinline__ u32 pk2(float a, float b) {
    u32 ua = __builtin_bit_cast(u32, a); ua += 0x7FFFu + ((ua >> 16) & 1u);
    u32 ub = __builtin_bit_cast(u32, b); ub += 0x7FFFu + ((ub >> 16) & 1u);
    return __builtin_amdgcn_perm(ub, ua, 0x07060302);  // {hi16(ub), hi16(ua)}
}
// hardware packed f32->bf16: dst.lo16 = bf16(lo), dst.hi16 = bf16(hi)
__device__ __forceinline__ u32 cvtpk(float lo, float hi) {
    u32 r;
    asm("v_cvt_pk_bf16_f32 %0, %1, %2" : "=v"(r) : "v"(lo), "v"(hi));
    return r;
}

#define GLDS(g, l) __builtin_amdgcn_global_load_lds( \
    (const __attribute__((address_space(1))) void*)(g), \
    (__attribute__((address_space(3))) void*)(l), 16, 0, 0)

// ---------------------------------------------------------------------------
__global__ __launch_bounds__(256) void wcvt(const float* __restrict__ s,
                                            u16* __restrict__ d, int n8) {
    const int i = blockIdx.x * 256 + threadIdx.x;
    if (i < n8) {
        const float4 f0 = ((const float4*)s)[2 * i];
        const float4 f1 = ((const float4*)s)[2 * i + 1];
        uint4 w;
        w.x = pk2(f0.x, f0.y); w.y = pk2(f0.z, f0.w);
        w.z = pk2(f1.x, f1.y); w.w = pk2(f1.z, f1.w);
        ((uint4*)d)[i] = w;
    }
}

__global__ __launch_bounds__(256) void wcvt3(const float* __restrict__ s0,
                                             const float* __restrict__ s1,
                                             const float* __restrict__ s2,
                                             u16* __restrict__ d0,
                                             u16* __restrict__ d1,
                                             u16* __restrict__ d2, int n8) {
    const int which = blockIdx.y;
    const float* s = (which == 0) ? s0 : (which == 1) ? s1 : s2;
    u16* d = (which == 0) ? d0 : (which == 1) ? d1 : d2;
    const int i = blockIdx.x * 256 + threadIdx.x;
    if (i < n8) {
        const float4 f0 = ((const float4*)s)[2 * i];
        const float4 f1 = ((const float4*)s)[2 * i + 1];
        uint4 w;
        w.x = pk2(f0.x, f0.y); w.y = pk2(f0.z, f0.w);
        w.z = pk2(f1.x, f1.y); w.w = pk2(f1.z, f1.w);
        ((uint4*)d)[i] = w;
    }
}

// ---------------------------------------------------------------------------
// GEMM out = A[8192,1024] @ W[N,1024]^T + bias. All-bf16, GLDS staging,
// 128x128 tile, BK=64, XOR chunk swizzle. PROJ=1: f32 out. PROJ=0: fused
// QKV (N=3072): Q rowmajor | K rowmajor | V^T [B,H,D,T].
// ---------------------------------------------------------------------------
template <int PROJ>
__global__ __launch_bounds__(256) void gemmX(const u16* __restrict__ A,
                                             const u16* __restrict__ Wb,
                                             const float* __restrict__ b0,
                                             const float* __restrict__ b1,
                                             const float* __restrict__ b2,
                                             void* __restrict__ out0,
                                             void* __restrict__ out1,
                                             void* __restrict__ out2) {
    __shared__ u16 As[128 * 64];
    __shared__ u16 Bs[128 * 64];

    const int tid  = threadIdx.x;
    const int wave = tid >> 6, lane = tid & 63;
    const int quad = lane >> 4, l16 = lane & 15;
    const int bm = blockIdx.y * 128, bn = blockIdx.x * 128;
    const int wm = (wave >> 1) * 64, wn = (wave & 1) * 64;
    const int K = CC;

    f32x4 acc[4][4] = {};

    for (int k0 = 0; k0 < K; k0 += 64) {
#pragma unroll
        for (int rr = 0; rr < 4; rr++) {
            const int c = rr * 256 + tid;
            const int row = c >> 3;
            const int cs = ((c & 7) ^ (row & 7)) * 8;
            GLDS(&Wb[(size_t)(bn + row) * K + k0 + cs], &Bs[c * 8]);
        }
#pragma unroll
        for (int rr = 0; rr < 4; rr++) {
            const int c = rr * 256 + tid;
            const int row = c >> 3;
            const int cs = ((c & 7) ^ (row & 7)) * 8;
            GLDS(&A[(size_t)(bm + row) * K + k0 + cs], &As[c * 8]);
        }
        __syncthreads();

#pragma unroll
        for (int ks = 0; ks < 2; ks++) {
            bf16x8 af[4], bfr[4];
#pragma unroll
            for (int i = 0; i < 4; i++) {
                const int row = wm + i * 16 + l16;
                const int s8 = (ks * 4 + quad) ^ (row & 7);
                af[i] = *(bf16x8*)&As[row * 64 + s8 * 8];
            }
#pragma unroll
            for (int j = 0; j < 4; j++) {
                const int row = wn + j * 16 + l16;
                const int s8 = (ks * 4 + quad) ^ (row & 7);
                bfr[j] = *(bf16x8*)&Bs[row * 64 + s8 * 8];
            }
#pragma unroll
            for (int i = 0; i < 4; i++)
#pragma unroll
                for (int j = 0; j < 4; j++)
                    acc[i][j] = __builtin_amdgcn_mfma_f32_16x16x32_bf16(af[i], bfr[j], acc[i][j], 0, 0, 0);
        }
        __syncthreads();
    }

    if (PROJ) {
        float* out = (float*)out0;
#pragma unroll
        for (int j = 0; j < 4; j++) {
            const int col = bn + wn + j * 16 + l16;
            const float bv = b0[col];
#pragma unroll
            for (int i = 0; i < 4; i++) {
                const int row0 = bm + wm + i * 16 + quad * 4;
#pragma unroll
                for (int r = 0; r < 4; r++)
                    out[(size_t)(row0 + r) * CC + col] = acc[i][j][r] + bv;
            }
        }
    } else {
        const int mid = bn >> 10;   // 0=Q,1=K,2=V (block-uniform)
        const float* bias = (mid == 0) ? b0 : (mid == 1) ? b1 : b2;
#pragma unroll
        for (int j = 0; j < 4; j++) {
            const int col  = bn + wn + j * 16 + l16;
            const int colL = col & (CC - 1);
            const float bv = bias[colL];
#pragma unroll
            for (int i = 0; i < 4; i++) {
                const int row0 = bm + wm + i * 16 + quad * 4;
                if (mid < 2) {
                    u16* out = (u16*)(mid ? out1 : out0);
#pragma unroll
                    for (int r = 0; r < 4; r++)
                        out[(size_t)(row0 + r) * CC + colL] = f2bf(acc[i][j][r] + bv);
                } else {
                    const int hh = colL >> 6, dch = colL & 63;
                    const int bb = row0 >> 11, t0 = row0 & (TT - 1);
                    const size_t idx = (((size_t)bb * HH + hh) * DD + dch) * TT + t0;
                    uint2 w;
                    w.x = pk2(acc[i][j][0] + bv, acc[i][j][1] + bv);
                    w.y = pk2(acc[i][j][2] + bv, acc[i][j][3] + bv);
                    *(uint2*)&((u16*)out2)[idx] = w;
                }
            }
        }
    }
}

// ---------------------------------------------------------------------------
// Flash attention. Block = (qt,h,b): 256 q-rows, 8 waves x 32 rows (2 m-frags).
// Swapped QK^T: S^T = mfma(K as A, Q as B). Key->A-row map per frag n:
// rowmap_n(i) = koff[n] + (i>>2)*8 + (i&3), koff={0,4,32,36}. C-layout
// (col=l16=q, row=quad*4+r=key-slot) gives lane (quad,l16) exactly keys
// {quad*8+0..7} u {32+quad*8+0..7} -> the PV A-fragment in-register.
// Ks [key][dim] sigma=((row>>3)&1)<<2|(row&3); Vs [d][key] sigma=row&7.
// Double-buffered GLDS (2/thread/tile at 512 thr), single raw barrier/tile,
// prefetch-first. ks-split softmax/PV interleave. No online max.
// ---------------------------------------------------------------------------
__global__ __launch_bounds__(512) void attn(const u16* __restrict__ Q,
                                            const u16* __restrict__ Kb,
                                            const u16* __restrict__ Vt,
                                            const int* __restrict__ mask,
                                            u16* __restrict__ Y) {
    const int b = blockIdx.z, h = blockIdx.y, qt = blockIdx.x;
    const int tid  = threadIdx.x;
    const int wave = tid >> 6, lane = tid & 63;
    const int quad = lane >> 4, l16 = lane & 15;
    const int qrow0 = qt * 256 + wave * 32;

    __shared__ u16 Ks[2][64 * 64];              // [key][dim]
    __shared__ u16 Vs[2][64 * 64];              // [d][key]
    __shared__ __align__(16) float bias_lds[TT];  // 0 or -1e38 per key

    const size_t qb = ((size_t)b * TT + qrow0) * CC + h * DD;

    bf16x8 qf[2][2];
#pragma unroll
    for (int m = 0; m < 2; m++)
#pragma unroll
        for (int ks = 0; ks < 2; ks++)
            qf[m][ks] = *(const bf16x8*)&Q[qb + (size_t)(m * 16 + l16) * CC + ks * 32 + quad * 8];

    // one-time mask -> bias table (4 keys per thread at 512 threads)
    {
        const int i = tid * 4;
        const int4 m0 = *(const int4*)&mask[b * TT + i];
        bias_lds[i + 0] = m0.x ? 0.f : -1e38f;
        bias_lds[i + 1] = m0.y ? 0.f : -1e38f;
        bias_lds[i + 2] = m0.z ? 0.f : -1e38f;
        bias_lds[i + 3] = m0.w ? 0.f : -1e38f;
    }

    // staging: slot c -> row=c>>3, pos=c&7; fetch global chunk pos^sigma(row)
    // 512 threads x 8 elems = 4096 = full 64x64 tile in one GLDS round.
    const int c0 = tid;
    const int r0 = c0 >> 3;
    const int kp0 = (c0 & 7) ^ ((((r0 >> 3) & 1) << 2) | (r0 & 3));
    const int vp0 = (c0 & 7) ^ (r0 & 7);
    const u16* kgp = Kb + ((size_t)b * TT) * CC + h * DD;
    const u16* vgp = Vt + ((size_t)(b * HH + h) * DD) * TT;

    // QK^T A-frag read geometry (same sigma for all koff)
    const int rowA = ((l16 >> 2) << 3) | (l16 & 3);
    const int s0k  = (((l16 >> 2) & 1) << 2) | (l16 & 3);

    f32x4 o[2][4] = {};
    float lsum[2] = {};
    const float SC = 0.18033688011112042f;   // 0.125 * log2(e)

    // prologue: stage tile 0 into buffer 0; drain vm (stage) + lgkm (bias)
    GLDS(&kgp[(size_t)r0 * CC + kp0 * 8], &Ks[0][c0 * 8]);
    GLDS(&vgp[(size_t)r0 * TT + vp0 * 8], &Vs[0][c0 * 8]);
    asm volatile("s_waitcnt vmcnt(0) lgkmcnt(0)" ::: "memory");
    __builtin_amdgcn_s_barrier();
    __builtin_amdgcn_sched_barrier(0);

#pragma unroll 1
    for (int kt = 0; kt < TT; kt += 64) {
        const int cur = (kt >> 6) & 1;
        const u16* Kc = &Ks[cur][0];
        const u16* Vc = &Vs[cur][0];

        // prefetch tile t+1 into the other buffer; in flight across compute
        if (kt + 64 < TT) {
            const int nxt = cur ^ 1;
            GLDS(&kgp[(size_t)(kt + 64 + r0) * CC + kp0 * 8], &Ks[nxt][c0 * 8]);
            GLDS(&vgp[(size_t)r0 * TT + kt + 64 + vp0 * 8], &Vs[nxt][c0 * 8]);
        }

        // bias for this tile's 16 lane-held keys (broadcast LDS reads)
        const f32x4 bA = *(const f32x4*)&bias_lds[kt + quad * 8];
        const f32x4 bB = *(const f32x4*)&bias_lds[kt + quad * 8 + 4];
        const f32x4 bC = *(const f32x4*)&bias_lds[kt + 32 + quad * 8];
        const f32x4 bD = *(const f32x4*)&bias_lds[kt + 32 + quad * 8 + 4];

        // ---- S^T = K Q^T : A=K (rowmap), B=Q ----
        f32x4 s2[2][4] = {};
        __builtin_amdgcn_s_setprio(1);
#pragma unroll
        for (int n = 0; n < 4; n++) {
            const int rowK = rowA + (n & 1) * 4 + (n >> 1) * 32;
#pragma unroll
            for (int ks = 0; ks < 2; ks++) {
                const int pos = ((ks << 2) + quad) ^ s0k;
                const bf16x8 kf = *(const bf16x8*)&Kc[rowK * 64 + pos * 8];
#pragma unroll
                for (int m = 0; m < 2; m++)
                    s2[m][n] = __builtin_amdgcn_mfma_f32_16x16x32_bf16(kf, qf[m][ks], s2[m][n], 0, 0, 0);
            }
        }
        __builtin_amdgcn_s_setprio(0);

        // ---- ks-split: softmax half -> PV half (shorter serial VALU run) --
        // s2[m][n][r] = S[q=m*16+l16][key = kt + (n&1)*4 + (n>>1)*32 + quad*8 + r]
#pragma unroll
        for (int ks = 0; ks < 2; ks++) {
            bf16x8 pf[2];
#pragma unroll
            for (int m = 0; m < 2; m++) {
                u32 pw[4];
#pragma unroll
                for (int nn = 0; nn < 2; nn++) {
                    const int n = 2 * ks + nn;
                    const f32x4 bv = (n == 0) ? bA : (n == 1) ? bB : (n == 2) ? bC : bD;
                    const float p0 = EXP2(fmaf(s2[m][n][0], SC, bv[0]));
                    const float p1 = EXP2(fmaf(s2[m][n][1], SC, bv[1]));
                    const float p2 = EXP2(fmaf(s2[m][n][2], SC, bv[2]));
                    const float p3 = EXP2(fmaf(s2[m][n][3], SC, bv[3]));
                    lsum[m] += (p0 + p1) + (p2 + p3);
                    pw[2 * nn]     = cvtpk(p0, p1);
                    pw[2 * nn + 1] = cvtpk(p2, p3);
                }
                const u32x4 t = { pw[0], pw[1], pw[2], pw[3] };
                pf[m] = __builtin_bit_cast(bf16x8, t);
            }
            __builtin_amdgcn_s_setprio(1);
#pragma unroll
            for (int dt = 0; dt < 4; dt++) {
                const int vrow = dt * 16 + l16;
                const int pos = ((ks << 2) + quad) ^ (vrow & 7);
                const bf16x8 vf = *(const bf16x8*)&Vc[vrow * 64 + pos * 8];
#pragma unroll
                for (int m = 0; m < 2; m++)
                    o[m][dt] = __builtin_amdgcn_mfma_f32_16x16x32_bf16(pf[m], vf, o[m][dt], 0, 0, 0);
            }
            __builtin_amdgcn_s_setprio(0);
        }

        // drain prefetch (had the whole compute phase to land), then sync.
        asm volatile("s_waitcnt vmcnt(0)" ::: "memory");
        __builtin_amdgcn_sched_barrier(0);
        __builtin_amdgcn_s_barrier();
    }

    // lsum[m] partial over this lane's 16 keys; sum across the 4 quads.
#pragma unroll
    for (int m = 0; m < 2; m++) {
        lsum[m] += __shfl_xor(lsum[m], 16, 64);
        lsum[m] += __shfl_xor(lsum[m], 32, 64);
    }

#pragma unroll
    for (int m = 0; m < 2; m++) {
        float inv[4];
#pragma unroll
        for (int r = 0; r < 4; r++)
            inv[r] = 1.0f / __shfl(lsum[m], quad * 4 + r, 64);  // lane l16=quad*4+r
#pragma unroll
        for (int dt = 0; dt < 4; dt++)
#pragma unroll
            for (int r = 0; r < 4; r++)
                Y[qb + (size_t)(m * 16 + quad * 4 + r) * CC + dt * 16 + l16] = f2bf(o[m][dt][r] * inv[r]);
    }
}

// ---------------------------------------------------------------------------
extern "C" void kernel_launch(void* const* d_in, const int* in_sizes, int n_in,
                              void* d_out, int out_size, void* d_ws, size_t ws_size,
                              hipStream_t stream) {
    const float* x    = (const float*)d_in[0];
    const int*   mask = (const int*)d_in[1];
    const float* Wq   = (const float*)d_in[2];
    const float* bq   = (const float*)d_in[3];
    const float* Wk   = (const float*)d_in[4];
    const float* bk   = (const float*)d_in[5];
    const float* Wv   = (const float*)d_in[6];
    const float* bv   = (const float*)d_in[7];
    const float* Wp   = (const float*)d_in[8];
    const float* bp   = (const float*)d_in[9];

    u16* ws = (u16*)d_ws;
    const size_t sz = (size_t)BB * TT * CC;     // 8,388,608 elems
    u16* Qb   = ws;              // Q; attn writes O here
    u16* Kbuf = ws + sz;         // K; reused for bf16 Wp after attn
    u16* Vtb  = ws + 2 * sz;     // V^T [B,H,D,T]   (ws total 48 MiB)

    u16* xb   = (u16*)d_out;     // squatters in d_out (dead by proj GEMM)
    u16* Wq16 = xb + sz;
    u16* Wk16 = Wq16 + (size_t)CC * CC;
    u16* Wv16 = Wk16 + (size_t)CC * CC;

    const int W8 = CC * CC / 8;      // 131072
    wcvt<<<4096, 256, 0, stream>>>(x, xb, (int)(sz / 8));
    wcvt3<<<dim3(512, 3), 256, 0, stream>>>(Wq, Wk, Wv, Wq16, Wk16, Wv16, W8);

    gemmX<0><<<dim3(24, 64), 256, 0, stream>>>(xb, Wq16, bq, bk, bv, Qb, Kbuf, Vtb);

    attn<<<dim3(TT / 256, HH, BB), 512, 0, stream>>>(Qb, Kbuf, Vtb, mask, Qb);

    wcvt<<<512, 256, 0, stream>>>(Wp, Kbuf, W8);   // K dead after attn
    gemmX<1><<<dim3(8, 64), 256, 0, stream>>>(Qb, Kbuf, bp, nullptr, nullptr, d_out, nullptr, nullptr);
}

// Round 4
// 288.929 us; speedup vs baseline: 1.0801x; 1.0019x over previous
//
#include <hip/hip_runtime.h>

// B=4, T=2048, C=1024, H=16, D=64. Device buffers f32 (mask int32).
// R13 = R12 (attn frozen) + GEMM/launch-count overhaul:
//   - gemm256: QKV GEMM at 256x256 tile, BK=64, 8 waves, 128KB dynamic-LDS
//     double-buffer, attn-proven pipeline (prefetch-first, raw s_barrier,
//     trailing vmcnt(0) after ~600cyc of compute), XOR chunk swizzle kept,
//     bijective XCD chunk swizzle (grid 384 = 12x32, 384%8==0).
//     Staging bytes per MFMA halved vs 128^2; drain now lands free.
//   - gemmP: proj GEMM (128^2, old 2-barrier structure) now reads Wp as f32
//     and converts during B staging (pk2 reg-stage) -> wcvt(Wp) launch gone.
//   - wcvtA: x + Wq/Wk/Wv conversions fused into ONE launch (5632 blocks).
//   - 6 launches -> 4.
// attn: identical to R12 (94us, MfmaUtil 30.7, conflicts 0, VGPR 60).

#define TT 2048
#define CC 1024
#define HH 16
#define DD 64
#define BB 4

typedef unsigned short u16;
typedef unsigned int u32;
typedef __attribute__((ext_vector_type(8))) short bf16x8;
typedef __attribute__((ext_vector_type(4))) float f32x4;
typedef __attribute__((ext_vector_type(4))) u32 u32x4;

#if __has_builtin(__builtin_amdgcn_exp2f)
#define EXP2(x) __builtin_amdgcn_exp2f(x)
#else
#define EXP2(x) __expf((x) * 0.6931471805599453f)
#endif

__device__ __forceinline__ u16 f2bf(float f) {
    u32 u = __builtin_bit_cast(u32, f);
    u += 0x7FFFu + ((u >> 16) & 1u);
    return (u16)(u >> 16);
}
__device__ __forceinline__ u32 pk2(float a, float b) {
    u32 ua = __builtin_bit_cast(u32, a); ua += 0x7FFFu + ((ua >> 16) & 1u);
    u32 ub = __builtin_bit_cast(u32, b); ub += 0x7FFFu + ((ub >> 16) & 1u);
    return __builtin_amdgcn_perm(ub, ua, 0x07060302);  // {hi16(ub), hi16(ua)}
}
// hardware packed f32->bf16: dst.lo16 = bf16(lo), dst.hi16 = bf16(hi)
__device__ __forceinline__ u32 cvtpk(float lo, float hi) {
    u32 r;
    asm("v_cvt_pk_bf16_f32 %0, %1, %2" : "=v"(r) : "v"(lo), "v"(hi));
    return r;
}

#define GLDS(g, l) __builtin_amdgcn_global_load_lds( \
    (const __attribute__((address_space(1))) void*)(g), \
    (__attribute__((address_space(3))) void*)(l), 16, 0, 0)

// ---------------------------------------------------------------------------
// Fused f32->bf16 conversions: x (4096 blocks) + Wq/Wk/Wv (3x512 blocks).
// All sizes are exact multiples of 256*8 -> no bounds checks.
// ---------------------------------------------------------------------------
__global__ __launch_bounds__(256) void wcvtA(const float* __restrict__ x,
                                             const float* __restrict__ Wq,
                                             const float* __restrict__ Wk,
                                             const float* __restrict__ Wv,
                                             u16* __restrict__ xb,
                                             u16* __restrict__ Wq16,
                                             u16* __restrict__ Wk16,
                                             u16* __restrict__ Wv16) {
    const int bid = blockIdx.x;
    const float* s; u16* d; int i;
    if (bid < 4096) {
        s = x; d = xb; i = bid * 256 + threadIdx.x;
    } else {
        const int t = bid - 4096;
        const int which = t >> 9, sub = t & 511;
        s = (which == 0) ? Wq : (which == 1) ? Wk : Wv;
        d = (which == 0) ? Wq16 : (which == 1) ? Wk16 : Wv16;
        i = sub * 256 + threadIdx.x;
    }
    const float4 f0 = ((const float4*)s)[2 * i];
    const float4 f1 = ((const float4*)s)[2 * i + 1];
    uint4 w;
    w.x = pk2(f0.x, f0.y); w.y = pk2(f0.z, f0.w);
    w.z = pk2(f1.x, f1.y); w.w = pk2(f1.z, f1.w);
    ((uint4*)d)[i] = w;
}

// ---------------------------------------------------------------------------
// QKV GEMM: out = A[8192,1024] @ W[3072,1024]^T + bias. 256x256 tile, BK=64,
// 8 waves (wr=wave>>2 in M, wc=wave&3 in N; per-wave 128x64 out), 128KB
// dynamic LDS, double-buffered, prefetch-first single-barrier pipeline.
// Output: Q rowmajor | K rowmajor | V^T [B,H,D,T] (block never crosses mid).
// ---------------------------------------------------------------------------
__global__ __launch_bounds__(512, 2) void gemm256(const u16* __restrict__ A,
                                                  const u16* __restrict__ Wb,
                                                  const float* __restrict__ b0,
                                                  const float* __restrict__ b1,
                                                  const float* __restrict__ b2,
                                                  u16* __restrict__ outQ,
                                                  u16* __restrict__ outK,
                                                  u16* __restrict__ outV) {
    extern __shared__ u16 lds[];   // A: [2][256][64] | B: [2][256][64] = 128KB
    const int tid  = threadIdx.x;
    const int wave = tid >> 6, lane = tid & 63;
    const int quad = lane >> 4, l16 = lane & 15;
    const int wr = wave >> 2, wc = wave & 3;

    // bijective XCD chunk swizzle over 12x32 = 384 blocks (384 % 8 == 0)
    const int bid0 = blockIdx.y * 12 + blockIdx.x;
    const int bid  = (bid0 & 7) * 48 + (bid0 >> 3);
    const int bn = (bid % 12) * 256, bm = (bid / 12) * 256;
    const int K = CC;

    u16* const As0 = lds;            // 2 x 16384 elems
    u16* const Bs0 = lds + 32768;    // 2 x 16384 elems

    // staging geometry: slot c -> row=c>>3 (0..255), chunk pos=c&7, sigma=row&7
    int rows[4], css[4];
#pragma unroll
    for (int g = 0; g < 4; g++) {
        const int c = g * 512 + tid;
        rows[g] = c >> 3;
        css[g]  = ((c & 7) ^ ((c >> 3) & 7)) * 8;
    }

    f32x4 acc[8][4] = {};

    auto STAGE = [&](int buf, int k0) {
#pragma unroll
        for (int g = 0; g < 4; g++)
            GLDS(&A[(size_t)(bm + rows[g]) * K + k0 + css[g]],
                 &As0[buf * 16384 + (g * 512 + tid) * 8]);
#pragma unroll
        for (int g = 0; g < 4; g++)
            GLDS(&Wb[(size_t)(bn + rows[g]) * K + k0 + css[g]],
                 &Bs0[buf * 16384 + (g * 512 + tid) * 8]);
    };

    // prologue
    STAGE(0, 0);
    asm volatile("s_waitcnt vmcnt(0)" ::: "memory");
    __builtin_amdgcn_s_barrier();
    __builtin_amdgcn_sched_barrier(0);

#pragma unroll 1
    for (int t = 0; t < 16; t++) {
        const int buf = t & 1;
        if (t < 15) STAGE(buf ^ 1, (t + 1) * 64);

        const u16* Ab = &As0[buf * 16384];
        const u16* Bb = &Bs0[buf * 16384];
        __builtin_amdgcn_s_setprio(1);
#pragma unroll
        for (int ks = 0; ks < 2; ks++) {
            bf16x8 bfr[4];
#pragma unroll
            for (int j = 0; j < 4; j++) {
                const int rb = wc * 64 + j * 16 + l16;
                const int p = ((ks << 2) + quad) ^ (rb & 7);
                bfr[j] = *(const bf16x8*)&Bb[rb * 64 + p * 8];
            }
#pragma unroll
            for (int i = 0; i < 8; i++) {
                const int ra = wr * 128 + i * 16 + l16;
                const int p = ((ks << 2) + quad) ^ (ra & 7);
                const bf16x8 af = *(const bf16x8*)&Ab[ra * 64 + p * 8];
#pragma unroll
                for (int j = 0; j < 4; j++)
                    acc[i][j] = __builtin_amdgcn_mfma_f32_16x16x32_bf16(af, bfr[j], acc[i][j], 0, 0, 0);
            }
        }
        __builtin_amdgcn_s_setprio(0);

        asm volatile("s_waitcnt vmcnt(0)" ::: "memory");
        __builtin_amdgcn_sched_barrier(0);
        __builtin_amdgcn_s_barrier();
    }

    // epilogue: Q/K rowmajor bf16, V -> V^T [B,H,D,T] bf16
    const int mid = bn >> 10;   // 0=Q,1=K,2=V (block-uniform; 256 | 1024)
    const float* bias = (mid == 0) ? b0 : (mid == 1) ? b1 : b2;
#pragma unroll
    for (int j = 0; j < 4; j++) {
        const int col  = bn + wc * 64 + j * 16 + l16;
        const int colL = col & (CC - 1);
        const float bv = bias[colL];
#pragma unroll
        for (int i = 0; i < 8; i++) {
            const int row0 = bm + wr * 128 + i * 16 + quad * 4;
            if (mid < 2) {
                u16* out = mid ? outK : outQ;
#pragma unroll
                for (int r = 0; r < 4; r++)
                    out[(size_t)(row0 + r) * CC + colL] = f2bf(acc[i][j][r] + bv);
            } else {
                const int hh = colL >> 6, dch = colL & 63;
                const int bb = row0 >> 11, t0 = row0 & (TT - 1);
                const size_t idx = (((size_t)bb * HH + hh) * DD + dch) * TT + t0;
                uint2 w;
                w.x = pk2(acc[i][j][0] + bv, acc[i][j][1] + bv);
                w.y = pk2(acc[i][j][2] + bv, acc[i][j][3] + bv);
                *(uint2*)&outV[idx] = w;
            }
        }
    }
}

// ---------------------------------------------------------------------------
// Proj GEMM: out_f32 = O[8192,1024] @ Wp[1024,1024]^T + bias. 128x128 tile,
// old 2-barrier structure; B staged from f32 Wp with inline conversion
// (kills the separate wcvt(Wp) launch). A (bf16 O) staged via GLDS.
// ---------------------------------------------------------------------------
__global__ __launch_bounds__(256) void gemmP(const u16* __restrict__ A,
                                             const float* __restrict__ Wf,
                                             const float* __restrict__ b0,
                                             float* __restrict__ out) {
    __shared__ u16 As[128 * 64];
    __shared__ u16 Bs[128 * 64];

    const int tid  = threadIdx.x;
    const int wave = tid >> 6, lane = tid & 63;
    const int quad = lane >> 4, l16 = lane & 15;
    const int bm = blockIdx.y * 128, bn = blockIdx.x * 128;
    const int wm = (wave >> 1) * 64, wn = (wave & 1) * 64;
    const int K = CC;

    f32x4 acc[4][4] = {};

    for (int k0 = 0; k0 < K; k0 += 64) {
#pragma unroll
        for (int rr = 0; rr < 4; rr++) {
            const int c = rr * 256 + tid;
            const int row = c >> 3;
            const int cs = ((c & 7) ^ (row & 7)) * 8;
            const float4 f0 = *(const float4*)&Wf[(size_t)(bn + row) * K + k0 + cs];
            const float4 f1 = *(const float4*)&Wf[(size_t)(bn + row) * K + k0 + cs + 4];
            uint4 w;
            w.x = pk2(f0.x, f0.y); w.y = pk2(f0.z, f0.w);
            w.z = pk2(f1.x, f1.y); w.w = pk2(f1.z, f1.w);
            *(uint4*)&Bs[c * 8] = w;
        }
#pragma unroll
        for (int rr = 0; rr < 4; rr++) {
            const int c = rr * 256 + tid;
            const int row = c >> 3;
            const int cs = ((c & 7) ^ (row & 7)) * 8;
            GLDS(&A[(size_t)(bm + row) * K + k0 + cs], &As[c * 8]);
        }
        __syncthreads();

#pragma unroll
        for (int ks = 0; ks < 2; ks++) {
            bf16x8 af[4], bfr[4];
#pragma unroll
            for (int i = 0; i < 4; i++) {
                const int row = wm + i * 16 + l16;
                const int s8 = (ks * 4 + quad) ^ (row & 7);
                af[i] = *(bf16x8*)&As[row * 64 + s8 * 8];
            }
#pragma unroll
            for (int j = 0; j < 4; j++) {
                const int row = wn + j * 16 + l16;
                const int s8 = (ks * 4 + quad) ^ (row & 7);
                bfr[j] = *(bf16x8*)&Bs[row * 64 + s8 * 8];
            }
#pragma unroll
            for (int i = 0; i < 4; i++)
#pragma unroll
                for (int j = 0; j < 4; j++)
                    acc[i][j] = __builtin_amdgcn_mfma_f32_16x16x32_bf16(af[i], bfr[j], acc[i][j], 0, 0, 0);
        }
        __syncthreads();
    }

#pragma unroll
    for (int j = 0; j < 4; j++) {
        const int col = bn + wn + j * 16 + l16;
        const float bv = b0[col];
#pragma unroll
        for (int i = 0; i < 4; i++) {
            const int row0 = bm + wm + i * 16 + quad * 4;
#pragma unroll
            for (int r = 0; r < 4; r++)
                out[(size_t)(row0 + r) * CC + col] = acc[i][j][r] + bv;
        }
    }
}

// ---------------------------------------------------------------------------
// Flash attention (identical to R12). Block = (qt,h,b): 256 q-rows,
// 8 waves x 32 rows. Swapped QK^T, in-register P, ks-split softmax/PV,
// double-buffered GLDS, single raw barrier per tile.
// ---------------------------------------------------------------------------
__global__ __launch_bounds__(512) void attn(const u16* __restrict__ Q,
                                            const u16* __restrict__ Kb,
                                            const u16* __restrict__ Vt,
                                            const int* __restrict__ mask,
                                            u16* __restrict__ Y) {
    const int b = blockIdx.z, h = blockIdx.y, qt = blockIdx.x;
    const int tid  = threadIdx.x;
    const int wave = tid >> 6, lane = tid & 63;
    const int quad = lane >> 4, l16 = lane & 15;
    const int qrow0 = qt * 256 + wave * 32;

    __shared__ u16 Ks[2][64 * 64];              // [key][dim]
    __shared__ u16 Vs[2][64 * 64];              // [d][key]
    __shared__ __align__(16) float bias_lds[TT];  // 0 or -1e38 per key

    const size_t qb = ((size_t)b * TT + qrow0) * CC + h * DD;

    bf16x8 qf[2][2];
#pragma unroll
    for (int m = 0; m < 2; m++)
#pragma unroll
        for (int ks = 0; ks < 2; ks++)
            qf[m][ks] = *(const bf16x8*)&Q[qb + (size_t)(m * 16 + l16) * CC + ks * 32 + quad * 8];

    // one-time mask -> bias table (4 keys per thread at 512 threads)
    {
        const int i = tid * 4;
        const int4 m0 = *(const int4*)&mask[b * TT + i];
        bias_lds[i + 0] = m0.x ? 0.f : -1e38f;
        bias_lds[i + 1] = m0.y ? 0.f : -1e38f;
        bias_lds[i + 2] = m0.z ? 0.f : -1e38f;
        bias_lds[i + 3] = m0.w ? 0.f : -1e38f;
    }

    const int c0 = tid;
    const int r0 = c0 >> 3;
    const int kp0 = (c0 & 7) ^ ((((r0 >> 3) & 1) << 2) | (r0 & 3));
    const int vp0 = (c0 & 7) ^ (r0 & 7);
    const u16* kgp = Kb + ((size_t)b * TT) * CC + h * DD;
    const u16* vgp = Vt + ((size_t)(b * HH + h) * DD) * TT;

    const int rowA = ((l16 >> 2) << 3) | (l16 & 3);
    const int s0k  = (((l16 >> 2) & 1) << 2) | (l16 & 3);

    f32x4 o[2][4] = {};
    float lsum[2] = {};
    const float SC = 0.18033688011112042f;   // 0.125 * log2(e)

    GLDS(&kgp[(size_t)r0 * CC + kp0 * 8], &Ks[0][c0 * 8]);
    GLDS(&vgp[(size_t)r0 * TT + vp0 * 8], &Vs[0][c0 * 8]);
    asm volatile("s_waitcnt vmcnt(0) lgkmcnt(0)" ::: "memory");
    __builtin_amdgcn_s_barrier();
    __builtin_amdgcn_sched_barrier(0);

#pragma unroll 1
    for (int kt = 0; kt < TT; kt += 64) {
        const int cur = (kt >> 6) & 1;
        const u16* Kc = &Ks[cur][0];
        const u16* Vc = &Vs[cur][0];

        if (kt + 64 < TT) {
            const int nxt = cur ^ 1;
            GLDS(&kgp[(size_t)(kt + 64 + r0) * CC + kp0 * 8], &Ks[nxt][c0 * 8]);
            GLDS(&vgp[(size_t)r0 * TT + kt + 64 + vp0 * 8], &Vs[nxt][c0 * 8]);
        }

        const f32x4 bA = *(const f32x4*)&bias_lds[kt + quad * 8];
        const f32x4 bB = *(const f32x4*)&bias_lds[kt + quad * 8 + 4];
        const f32x4 bC = *(const f32x4*)&bias_lds[kt + 32 + quad * 8];
        const f32x4 bD = *(const f32x4*)&bias_lds[kt + 32 + quad * 8 + 4];

        f32x4 s2[2][4] = {};
        __builtin_amdgcn_s_setprio(1);
#pragma unroll
        for (int n = 0; n < 4; n++) {
            const int rowK = rowA + (n & 1) * 4 + (n >> 1) * 32;
#pragma unroll
            for (int ks = 0; ks < 2; ks++) {
                const int pos = ((ks << 2) + quad) ^ s0k;
                const bf16x8 kf = *(const bf16x8*)&Kc[rowK * 64 + pos * 8];
#pragma unroll
                for (int m = 0; m < 2; m++)
                    s2[m][n] = __builtin_amdgcn_mfma_f32_16x16x32_bf16(kf, qf[m][ks], s2[m][n], 0, 0, 0);
            }
        }
        __builtin_amdgcn_s_setprio(0);

#pragma unroll
        for (int ks = 0; ks < 2; ks++) {
            bf16x8 pf[2];
#pragma unroll
            for (int m = 0; m < 2; m++) {
                u32 pw[4];
#pragma unroll
                for (int nn = 0; nn < 2; nn++) {
                    const int n = 2 * ks + nn;
                    const f32x4 bv = (n == 0) ? bA : (n == 1) ? bB : (n == 2) ? bC : bD;
                    const float p0 = EXP2(fmaf(s2[m][n][0], SC, bv[0]));
                    const float p1 = EXP2(fmaf(s2[m][n][1], SC, bv[1]));
                    const float p2 = EXP2(fmaf(s2[m][n][2], SC, bv[2]));
                    const float p3 = EXP2(fmaf(s2[m][n][3], SC, bv[3]));
                    lsum[m] += (p0 + p1) + (p2 + p3);
                    pw[2 * nn]     = cvtpk(p0, p1);
                    pw[2 * nn + 1] = cvtpk(p2, p3);
                }
                const u32x4 t = { pw[0], pw[1], pw[2], pw[3] };
                pf[m] = __builtin_bit_cast(bf16x8, t);
            }
            __builtin_amdgcn_s_setprio(1);
#pragma unroll
            for (int dt = 0; dt < 4; dt++) {
                const int vrow = dt * 16 + l16;
                const int pos = ((ks << 2) + quad) ^ (vrow & 7);
                const bf16x8 vf = *(const bf16x8*)&Vc[vrow * 64 + pos * 8];
#pragma unroll
                for (int m = 0; m < 2; m++)
                    o[m][dt] = __builtin_amdgcn_mfma_f32_16x16x32_bf16(pf[m], vf, o[m][dt], 0, 0, 0);
            }
            __builtin_amdgcn_s_setprio(0);
        }

        asm volatile("s_waitcnt vmcnt(0)" ::: "memory");
        __builtin_amdgcn_sched_barrier(0);
        __builtin_amdgcn_s_barrier();
    }

#pragma unroll
    for (int m = 0; m < 2; m++) {
        lsum[m] += __shfl_xor(lsum[m], 16, 64);
        lsum[m] += __shfl_xor(lsum[m], 32, 64);
    }

#pragma unroll
    for (int m = 0; m < 2; m++) {
        float inv[4];
#pragma unroll
        for (int r = 0; r < 4; r++)
            inv[r] = 1.0f / __shfl(lsum[m], quad * 4 + r, 64);
#pragma unroll
        for (int dt = 0; dt < 4; dt++)
#pragma unroll
            for (int r = 0; r < 4; r++)
                Y[qb + (size_t)(m * 16 + quad * 4 + r) * CC + dt * 16 + l16] = f2bf(o[m][dt][r] * inv[r]);
    }
}

// ---------------------------------------------------------------------------
extern "C" void kernel_launch(void* const* d_in, const int* in_sizes, int n_in,
                              void* d_out, int out_size, void* d_ws, size_t ws_size,
                              hipStream_t stream) {
    const float* x    = (const float*)d_in[0];
    const int*   mask = (const int*)d_in[1];
    const float* Wq   = (const float*)d_in[2];
    const float* bq   = (const float*)d_in[3];
    const float* Wk   = (const float*)d_in[4];
    const float* bk   = (const float*)d_in[5];
    const float* Wv   = (const float*)d_in[6];
    const float* bv   = (const float*)d_in[7];
    const float* Wp   = (const float*)d_in[8];
    const float* bp   = (const float*)d_in[9];

    u16* ws = (u16*)d_ws;
    const size_t sz = (size_t)BB * TT * CC;     // 8,388,608 elems
    u16* Qb   = ws;              // Q; attn writes O here
    u16* Kbuf = ws + sz;         // K
    u16* Vtb  = ws + 2 * sz;     // V^T [B,H,D,T]   (ws total 48 MiB)

    u16* xb   = (u16*)d_out;     // squatters in d_out (dead by proj GEMM)
    u16* Wq16 = xb + sz;
    u16* Wk16 = Wq16 + (size_t)CC * CC;
    u16* Wv16 = Wk16 + (size_t)CC * CC;   // Wq16..Wv16 contiguous = W[3072][1024]

    static bool inited = false;
    if (!inited) {
        (void)hipFuncSetAttribute((const void*)gemm256,
                                  hipFuncAttributeMaxDynamicSharedMemorySize, 131072);
        inited = true;
    }

    wcvtA<<<5632, 256, 0, stream>>>(x, Wq, Wk, Wv, xb, Wq16, Wk16, Wv16);

    gemm256<<<dim3(12, 32), 512, 131072, stream>>>(xb, Wq16, bq, bk, bv, Qb, Kbuf, Vtb);

    attn<<<dim3(TT / 256, HH, BB), 512, 0, stream>>>(Qb, Kbuf, Vtb, mask, Qb);

    gemmP<<<dim3(8, 64), 256, 0, stream>>>(Qb, Wp, bp, (float*)d_out);
}

// Round 5
// 279.101 us; speedup vs baseline: 1.1181x; 1.0352x over previous
//
#include <hip/hip_runtime.h>

// B=4, T=2048, C=1024, H=16, D=64. Device buffers f32 (mask int32).
// R15 = R14 with the GEMMs rebuilt around T4 (counted vmcnt, never drain):
//   gemmT<BN,WM,WN,MODE>: 256xBN tile, BK=32, FOUR LDS buffers, staging
//   lead = 3 K-tiles. Per iter: stage(t+3) -> ds_read+MFMA(t) ->
//   s_waitcnt vmcnt(2*SPT) (waits tile t+1 only; t+2/t+3 loads stay in
//   flight ACROSS the barrier) -> s_barrier. Tail 3 iters drain 2S->S->0.
//   R14's 2-phase vmcnt(0) drain (the ~70% critical-path stall, m233) gone.
//   QKV: <256,128,64,0>, grid 12x32, LDS 128KB. Proj: <128,64,64,1>,
//   grid 8x32 (=256 blocks = exactly 1 CU round), LDS 96KB, bf16 Wp via
//   small wcvt after attn (Kbuf dead). Swizzle sigma(row)=(row>>1)&3 on
//   4-chunk rows (64B): uniform 8-lane-per-bank-group = b128 floor.
// attn: frozen at R12 (94.5us, MfmaUtil 30.8, conflicts 0).

#define TT 2048
#define CC 1024
#define HH 16
#define DD 64
#define BB 4

typedef unsigned short u16;
typedef unsigned int u32;
typedef __attribute__((ext_vector_type(8))) short bf16x8;
typedef __attribute__((ext_vector_type(4))) float f32x4;
typedef __attribute__((ext_vector_type(4))) u32 u32x4;

#if __has_builtin(__builtin_amdgcn_exp2f)
#define EXP2(x) __builtin_amdgcn_exp2f(x)
#else
#define EXP2(x) __expf((x) * 0.6931471805599453f)
#endif

__device__ __forceinline__ u16 f2bf(float f) {
    u32 u = __builtin_bit_cast(u32, f);
    u += 0x7FFFu + ((u >> 16) & 1u);
    return (u16)(u >> 16);
}
__device__ __forceinline__ u32 pk2(float a, float b) {
    u32 ua = __builtin_bit_cast(u32, a); ua += 0x7FFFu + ((ua >> 16) & 1u);
    u32 ub = __builtin_bit_cast(u32, b); ub += 0x7FFFu + ((ub >> 16) & 1u);
    return __builtin_amdgcn_perm(ub, ua, 0x07060302);  // {hi16(ub), hi16(ua)}
}
__device__ __forceinline__ u32 cvtpk(float lo, float hi) {
    u32 r;
    asm("v_cvt_pk_bf16_f32 %0, %1, %2" : "=v"(r) : "v"(lo), "v"(hi));
    return r;
}

#define GLDS(g, l) __builtin_amdgcn_global_load_lds( \
    (const __attribute__((address_space(1))) void*)(g), \
    (__attribute__((address_space(3))) void*)(l), 16, 0, 0)

// ---------------------------------------------------------------------------
__global__ __launch_bounds__(256) void wcvt(const float* __restrict__ s,
                                            u16* __restrict__ d, int n8) {
    const int i = blockIdx.x * 256 + threadIdx.x;
    if (i < n8) {
        const float4 f0 = ((const float4*)s)[2 * i];
        const float4 f1 = ((const float4*)s)[2 * i + 1];
        uint4 w;
        w.x = pk2(f0.x, f0.y); w.y = pk2(f0.z, f0.w);
        w.z = pk2(f1.x, f1.y); w.w = pk2(f1.z, f1.w);
        ((uint4*)d)[i] = w;
    }
}

// Fused f32->bf16: x (4096 blocks) + Wq/Wk/Wv (3x512 blocks).
__global__ __launch_bounds__(256) void wcvtA(const float* __restrict__ x,
                                             const float* __restrict__ Wq,
                                             const float* __restrict__ Wk,
                                             const float* __restrict__ Wv,
                                             u16* __restrict__ xb,
                                             u16* __restrict__ Wq16,
                                             u16* __restrict__ Wk16,
                                             u16* __restrict__ Wv16) {
    const int bid = blockIdx.x;
    const float* s; u16* d; int i;
    if (bid < 4096) {
        s = x; d = xb; i = bid * 256 + threadIdx.x;
    } else {
        const int t = bid - 4096;
        const int which = t >> 9, sub = t & 511;
        s = (which == 0) ? Wq : (which == 1) ? Wk : Wv;
        d = (which == 0) ? Wq16 : (which == 1) ? Wk16 : Wv16;
        i = sub * 256 + threadIdx.x;
    }
    const float4 f0 = ((const float4*)s)[2 * i];
    const float4 f1 = ((const float4*)s)[2 * i + 1];
    uint4 w;
    w.x = pk2(f0.x, f0.y); w.y = pk2(f0.z, f0.w);
    w.z = pk2(f1.x, f1.y); w.w = pk2(f1.z, f1.w);
    ((uint4*)d)[i] = w;
}

// ---------------------------------------------------------------------------
// Pipelined GEMM: out = A[8192,1024] @ W[N,1024]^T + bias.
// 256 x BN tile, BK=32, 8 waves (WAVES_M x WAVES_N = (256/WM) x (BN/WN)),
// 4 LDS buffers, stage lead 3 tiles, counted vmcnt (T4): main-loop wait is
// vmcnt(2*SPT) = "tile t+1 landed, t+2/t+3 still in flight".
// MODE 0: QKV fused (bf16: Q rowmajor | K rowmajor | V^T [B,H,D,T]).
// MODE 1: proj (f32 out + bias).
// ---------------------------------------------------------------------------
template <int BN, int WM, int WN, int MODE>
__global__ __launch_bounds__(512, 2) void gemmT(const u16* __restrict__ Ag,
                                                const u16* __restrict__ Bg,
                                                const float* __restrict__ b0,
                                                const float* __restrict__ b1,
                                                const float* __restrict__ b2,
                                                u16* __restrict__ outQ,
                                                u16* __restrict__ outK,
                                                u16* __restrict__ outV,
                                                float* __restrict__ outF) {
    constexpr int NI = WM / 16, NJ = WN / 16;
    constexpr int WAVES_N = BN / WN;
    constexpr int BUFSZ = (256 + BN) * 32;        // elems per buffer
    constexpr int SPT = 2 + BN / 128;             // GLDS per thread per tile
    constexpr int NT = CC / 32;                   // 32 K-tiles

    extern __shared__ u16 lds[];                  // 4 * BUFSZ elems
    const int tid  = threadIdx.x;
    const int wave = tid >> 6, lane = tid & 63;
    const int quad = lane >> 4, l16 = lane & 15;
    const int wr = wave / WAVES_N, wc = wave & (WAVES_N - 1);

    // bijective XCD chunk swizzle (grid size % 8 == 0 in both modes)
    const int NBX = (BN == 256) ? 12 : 8;
    const int bid0 = blockIdx.y * NBX + blockIdx.x;
    const int chunk = (NBX * 32) >> 3;
    const int bid  = (bid0 & 7) * chunk + (bid0 >> 3);
    const int bn = (bid % NBX) * BN, bm = (bid / NBX) * 256;

    // ---- thread-constant staging geometry: slot c -> row=c>>2, pos=c&3,
    // fetch global chunk kc = pos ^ sigma(row), sigma(row)=(row>>1)&3 ----
    size_t aOff[2]; int aDst[2];
#pragma unroll
    for (int g = 0; g < 2; g++) {
        const int c = g * 512 + tid;
        const int row = c >> 2;
        const int kc = (c & 3) ^ ((row >> 1) & 3);
        aOff[g] = (size_t)(bm + row) * CC + kc * 8;
        aDst[g] = c * 8;
    }
    size_t bOff[BN / 128]; int bDst[BN / 128];
#pragma unroll
    for (int g = 0; g < BN / 128; g++) {
        const int c = g * 512 + tid;
        const int row = c >> 2;
        const int kc = (c & 3) ^ ((row >> 1) & 3);
        bOff[g] = (size_t)(bn + row) * CC + kc * 8;
        bDst[g] = 8192 + c * 8;
    }

    // ---- thread-constant fragment-read offsets (elems) ----
    int aRd[NI], bRd[NJ];
#pragma unroll
    for (int i = 0; i < NI; i++) {
        const int row = wr * WM + i * 16 + l16;
        const int p = quad ^ ((row >> 1) & 3);
        aRd[i] = row * 32 + p * 8;
    }
#pragma unroll
    for (int j = 0; j < NJ; j++) {
        const int row = wc * WN + j * 16 + l16;
        const int p = quad ^ ((row >> 1) & 3);
        bRd[j] = 8192 + row * 32 + p * 8;
    }

    f32x4 acc[NI][NJ] = {};

#define STAGE_T(t)                                                        \
    {                                                                     \
        u16* dst = &lds[((t) & 3) * BUFSZ];                               \
        const int k0 = (t) * 32;                                          \
        _Pragma("unroll")                                                 \
        for (int g = 0; g < 2; g++)                                       \
            GLDS(&Ag[aOff[g] + k0], &dst[aDst[g]]);                       \
        _Pragma("unroll")                                                 \
        for (int g = 0; g < BN / 128; g++)                                \
            GLDS(&Bg[bOff[g] + k0], &dst[bDst[g]]);                       \
    }

#define COMPUTE_T(t)                                                      \
    {                                                                     \
        const u16* buf = &lds[((t) & 3) * BUFSZ];                         \
        bf16x8 af[NI], bfr[NJ];                                           \
        _Pragma("unroll")                                                 \
        for (int i = 0; i < NI; i++) af[i] = *(const bf16x8*)&buf[aRd[i]];\
        _Pragma("unroll")                                                 \
        for (int j = 0; j < NJ; j++) bfr[j] = *(const bf16x8*)&buf[bRd[j]];\
        __builtin_amdgcn_s_setprio(1);                                    \
        _Pragma("unroll")                                                 \
        for (int i = 0; i < NI; i++)                                      \
            _Pragma("unroll")                                             \
            for (int j = 0; j < NJ; j++)                                  \
                acc[i][j] = __builtin_amdgcn_mfma_f32_16x16x32_bf16(      \
                    af[i], bfr[j], acc[i][j], 0, 0, 0);                   \
        __builtin_amdgcn_s_setprio(0);                                    \
    }

#define WAIT_MAIN()                                                       \
    if constexpr (SPT == 4) asm volatile("s_waitcnt vmcnt(8)" ::: "memory"); \
    else                    asm volatile("s_waitcnt vmcnt(6)" ::: "memory");
#define WAIT_ONE()                                                        \
    if constexpr (SPT == 4) asm volatile("s_waitcnt vmcnt(4)" ::: "memory"); \
    else                    asm volatile("s_waitcnt vmcnt(3)" ::: "memory");

    // prologue: stage tiles 0,1,2; wait tile0 (tiles 1,2 stay in flight)
    STAGE_T(0); STAGE_T(1); STAGE_T(2);
    WAIT_MAIN();
    __builtin_amdgcn_sched_barrier(0);
    __builtin_amdgcn_s_barrier();
    __builtin_amdgcn_sched_barrier(0);

#pragma unroll 1
    for (int t = 0; t < NT - 3; t++) {
        STAGE_T(t + 3);
        COMPUTE_T(t);
        WAIT_MAIN();
        __builtin_amdgcn_sched_barrier(0);
        __builtin_amdgcn_s_barrier();
        __builtin_amdgcn_sched_barrier(0);
    }
    // tail: tiles NT-3, NT-2, NT-1 (no new stages; drain 2S -> S -> 0)
    COMPUTE_T(NT - 3);
    WAIT_ONE();
    __builtin_amdgcn_sched_barrier(0);
    __builtin_amdgcn_s_barrier();
    __builtin_amdgcn_sched_barrier(0);
    COMPUTE_T(NT - 2);
    asm volatile("s_waitcnt vmcnt(0)" ::: "memory");
    __builtin_amdgcn_sched_barrier(0);
    __builtin_amdgcn_s_barrier();
    __builtin_amdgcn_sched_barrier(0);
    COMPUTE_T(NT - 1);

#undef STAGE_T
#undef COMPUTE_T
#undef WAIT_MAIN
#undef WAIT_ONE

    // ---- epilogue ----
    if (MODE == 1) {
#pragma unroll
        for (int j = 0; j < NJ; j++) {
            const int col = bn + wc * WN + j * 16 + l16;
            const float bv = b0[col];
#pragma unroll
            for (int i = 0; i < NI; i++) {
                const int row0 = bm + wr * WM + i * 16 + quad * 4;
#pragma unroll
                for (int r = 0; r < 4; r++)
                    outF[(size_t)(row0 + r) * CC + col] = acc[i][j][r] + bv;
            }
        }
    } else {
        const int mid = bn >> 10;   // 0=Q,1=K,2=V (block-uniform; BN=256 | 1024)
        const float* bias = (mid == 0) ? b0 : (mid == 1) ? b1 : b2;
#pragma unroll
        for (int j = 0; j < NJ; j++) {
            const int col  = bn + wc * WN + j * 16 + l16;
            const int colL = col & (CC - 1);
            const float bv = bias[colL];
#pragma unroll
            for (int i = 0; i < NI; i++) {
                const int row0 = bm + wr * WM + i * 16 + quad * 4;
                if (mid < 2) {
                    u16* out = mid ? outK : outQ;
#pragma unroll
                    for (int r = 0; r < 4; r++)
                        out[(size_t)(row0 + r) * CC + colL] = f2bf(acc[i][j][r] + bv);
                } else {
                    const int hh = colL >> 6, dch = colL & 63;
                    const int bb = row0 >> 11, t0 = row0 & (TT - 1);
                    const size_t idx = (((size_t)bb * HH + hh) * DD + dch) * TT + t0;
                    uint2 w;
                    w.x = pk2(acc[i][j][0] + bv, acc[i][j][1] + bv);
                    w.y = pk2(acc[i][j][2] + bv, acc[i][j][3] + bv);
                    *(uint2*)&outV[idx] = w;
                }
            }
        }
    }
}

// ---------------------------------------------------------------------------
// Flash attention (frozen since R12). Block = (qt,h,b): 256 q-rows,
// 8 waves x 32 rows. Swapped QK^T, in-register P, ks-split softmax/PV,
// double-buffered GLDS, single raw barrier per tile.
// ---------------------------------------------------------------------------
__global__ __launch_bounds__(512) void attn(const u16* __restrict__ Q,
                                            const u16* __restrict__ Kb,
                                            const u16* __restrict__ Vt,
                                            const int* __restrict__ mask,
                                            u16* __restrict__ Y) {
    const int b = blockIdx.z, h = blockIdx.y, qt = blockIdx.x;
    const int tid  = threadIdx.x;
    const int wave = tid >> 6, lane = tid & 63;
    const int quad = lane >> 4, l16 = lane & 15;
    const int qrow0 = qt * 256 + wave * 32;

    __shared__ u16 Ks[2][64 * 64];              // [key][dim]
    __shared__ u16 Vs[2][64 * 64];              // [d][key]
    __shared__ __align__(16) float bias_lds[TT];  // 0 or -1e38 per key

    const size_t qb = ((size_t)b * TT + qrow0) * CC + h * DD;

    bf16x8 qf[2][2];
#pragma unroll
    for (int m = 0; m < 2; m++)
#pragma unroll
        for (int ks = 0; ks < 2; ks++)
            qf[m][ks] = *(const bf16x8*)&Q[qb + (size_t)(m * 16 + l16) * CC + ks * 32 + quad * 8];

    {
        const int i = tid * 4;
        const int4 m0 = *(const int4*)&mask[b * TT + i];
        bias_lds[i + 0] = m0.x ? 0.f : -1e38f;
        bias_lds[i + 1] = m0.y ? 0.f : -1e38f;
        bias_lds[i + 2] = m0.z ? 0.f : -1e38f;
        bias_lds[i + 3] = m0.w ? 0.f : -1e38f;
    }

    const int c0 = tid;
    const int r0 = c0 >> 3;
    const int kp0 = (c0 & 7) ^ ((((r0 >> 3) & 1) << 2) | (r0 & 3));
    const int vp0 = (c0 & 7) ^ (r0 & 7);
    const u16* kgp = Kb + ((size_t)b * TT) * CC + h * DD;
    const u16* vgp = Vt + ((size_t)(b * HH + h) * DD) * TT;

    const int rowA = ((l16 >> 2) << 3) | (l16 & 3);
    const int s0k  = (((l16 >> 2) & 1) << 2) | (l16 & 3);

    f32x4 o[2][4] = {};
    float lsum[2] = {};
    const float SC = 0.18033688011112042f;   // 0.125 * log2(e)

    GLDS(&kgp[(size_t)r0 * CC + kp0 * 8], &Ks[0][c0 * 8]);
    GLDS(&vgp[(size_t)r0 * TT + vp0 * 8], &Vs[0][c0 * 8]);
    asm volatile("s_waitcnt vmcnt(0) lgkmcnt(0)" ::: "memory");
    __builtin_amdgcn_s_barrier();
    __builtin_amdgcn_sched_barrier(0);

#pragma unroll 1
    for (int kt = 0; kt < TT; kt += 64) {
        const int cur = (kt >> 6) & 1;
        const u16* Kc = &Ks[cur][0];
        const u16* Vc = &Vs[cur][0];

        if (kt + 64 < TT) {
            const int nxt = cur ^ 1;
            GLDS(&kgp[(size_t)(kt + 64 + r0) * CC + kp0 * 8], &Ks[nxt][c0 * 8]);
            GLDS(&vgp[(size_t)r0 * TT + kt + 64 + vp0 * 8], &Vs[nxt][c0 * 8]);
        }

        const f32x4 bA = *(const f32x4*)&bias_lds[kt + quad * 8];
        const f32x4 bB = *(const f32x4*)&bias_lds[kt + quad * 8 + 4];
        const f32x4 bC = *(const f32x4*)&bias_lds[kt + 32 + quad * 8];
        const f32x4 bD = *(const f32x4*)&bias_lds[kt + 32 + quad * 8 + 4];

        f32x4 s2[2][4] = {};
        __builtin_amdgcn_s_setprio(1);
#pragma unroll
        for (int n = 0; n < 4; n++) {
            const int rowK = rowA + (n & 1) * 4 + (n >> 1) * 32;
#pragma unroll
            for (int ks = 0; ks < 2; ks++) {
                const int pos = ((ks << 2) + quad) ^ s0k;
                const bf16x8 kf = *(const bf16x8*)&Kc[rowK * 64 + pos * 8];
#pragma unroll
                for (int m = 0; m < 2; m++)
                    s2[m][n] = __builtin_amdgcn_mfma_f32_16x16x32_bf16(kf, qf[m][ks], s2[m][n], 0, 0, 0);
            }
        }
        __builtin_amdgcn_s_setprio(0);

#pragma unroll
        for (int ks = 0; ks < 2; ks++) {
            bf16x8 pf[2];
#pragma unroll
            for (int m = 0; m < 2; m++) {
                u32 pw[4];
#pragma unroll
                for (int nn = 0; nn < 2; nn++) {
                    const int n = 2 * ks + nn;
                    const f32x4 bv = (n == 0) ? bA : (n == 1) ? bB : (n == 2) ? bC : bD;
                    const float p0 = EXP2(fmaf(s2[m][n][0], SC, bv[0]));
                    const float p1 = EXP2(fmaf(s2[m][n][1], SC, bv[1]));
                    const float p2 = EXP2(fmaf(s2[m][n][2], SC, bv[2]));
                    const float p3 = EXP2(fmaf(s2[m][n][3], SC, bv[3]));
                    lsum[m] += (p0 + p1) + (p2 + p3);
                    pw[2 * nn]     = cvtpk(p0, p1);
                    pw[2 * nn + 1] = cvtpk(p2, p3);
                }
                const u32x4 t = { pw[0], pw[1], pw[2], pw[3] };
                pf[m] = __builtin_bit_cast(bf16x8, t);
            }
            __builtin_amdgcn_s_setprio(1);
#pragma unroll
            for (int dt = 0; dt < 4; dt++) {
                const int vrow = dt * 16 + l16;
                const int pos = ((ks << 2) + quad) ^ (vrow & 7);
                const bf16x8 vf = *(const bf16x8*)&Vc[vrow * 64 + pos * 8];
#pragma unroll
                for (int m = 0; m < 2; m++)
                    o[m][dt] = __builtin_amdgcn_mfma_f32_16x16x32_bf16(pf[m], vf, o[m][dt], 0, 0, 0);
            }
            __builtin_amdgcn_s_setprio(0);
        }

        asm volatile("s_waitcnt vmcnt(0)" ::: "memory");
        __builtin_amdgcn_sched_barrier(0);
        __builtin_amdgcn_s_barrier();
    }

#pragma unroll
    for (int m = 0; m < 2; m++) {
        lsum[m] += __shfl_xor(lsum[m], 16, 64);
        lsum[m] += __shfl_xor(lsum[m], 32, 64);
    }

#pragma unroll
    for (int m = 0; m < 2; m++) {
        float inv[4];
#pragma unroll
        for (int r = 0; r < 4; r++)
            inv[r] = 1.0f / __shfl(lsum[m], quad * 4 + r, 64);
#pragma unroll
        for (int dt = 0; dt < 4; dt++)
#pragma unroll
            for (int r = 0; r < 4; r++)
                Y[qb + (size_t)(m * 16 + quad * 4 + r) * CC + dt * 16 + l16] = f2bf(o[m][dt][r] * inv[r]);
    }
}

// ---------------------------------------------------------------------------
extern "C" void kernel_launch(void* const* d_in, const int* in_sizes, int n_in,
                              void* d_out, int out_size, void* d_ws, size_t ws_size,
                              hipStream_t stream) {
    const float* x    = (const float*)d_in[0];
    const int*   mask = (const int*)d_in[1];
    const float* Wq   = (const float*)d_in[2];
    const float* bq   = (const float*)d_in[3];
    const float* Wk   = (const float*)d_in[4];
    const float* bk   = (const float*)d_in[5];
    const float* Wv   = (const float*)d_in[6];
    const float* bv   = (const float*)d_in[7];
    const float* Wp   = (const float*)d_in[8];
    const float* bp   = (const float*)d_in[9];

    u16* ws = (u16*)d_ws;
    const size_t sz = (size_t)BB * TT * CC;     // 8,388,608 elems
    u16* Qb   = ws;              // Q; attn writes O here
    u16* Kbuf = ws + sz;         // K; reused for bf16 Wp after attn
    u16* Vtb  = ws + 2 * sz;     // V^T [B,H,D,T]   (ws total 48 MiB)

    u16* xb   = (u16*)d_out;     // squatters in d_out (dead by proj GEMM)
    u16* Wq16 = xb + sz;
    u16* Wk16 = Wq16 + (size_t)CC * CC;
    u16* Wv16 = Wk16 + (size_t)CC * CC;   // Wq16..Wv16 contiguous = W[3072][1024]

    static bool inited = false;
    if (!inited) {
        (void)hipFuncSetAttribute((const void*)gemmT<256, 128, 64, 0>,
                                  hipFuncAttributeMaxDynamicSharedMemorySize, 131072);
        (void)hipFuncSetAttribute((const void*)gemmT<128, 64, 64, 1>,
                                  hipFuncAttributeMaxDynamicSharedMemorySize, 98304);
        inited = true;
    }

    const int W8 = CC * CC / 8;      // 131072

    wcvtA<<<5632, 256, 0, stream>>>(x, Wq, Wk, Wv, xb, Wq16, Wk16, Wv16);

    gemmT<256, 128, 64, 0><<<dim3(12, 32), 512, 131072, stream>>>(
        xb, Wq16, bq, bk, bv, Qb, Kbuf, Vtb, nullptr);

    attn<<<dim3(TT / 256, HH, BB), 512, 0, stream>>>(Qb, Kbuf, Vtb, mask, Qb);

    wcvt<<<512, 256, 0, stream>>>(Wp, Kbuf, W8);   // Kbuf dead after attn

    gemmT<128, 64, 64, 1><<<dim3(8, 32), 512, 98304, stream>>>(
        Qb, Kbuf, bp, nullptr, nullptr, nullptr, nullptr, nullptr, (float*)d_out);
}

// Round 6
// 266.376 us; speedup vs baseline: 1.1716x; 1.0478x over previous
//
#include <hip/hip_runtime.h>

// B=4, T=2048, C=1024, H=16, D=64. Device buffers f32 (mask int32).
// R16 = R15 with the GEMM occupancy/balance fix (the attn-R12 lesson, TLP):
//   - gemmT: 4 -> 3 LDS buffers (stage lead 2, issue->use ~2 compute phases
//     > HBM latency). LDS 128KB -> 72KB  => 2 blocks/CU co-resident: when
//     one block is at its barrier, the other block's waves feed the pipes.
//   - QKV tile 256x256 -> 256x128: grid 24x32 = 768 blocks = exactly 3/CU,
//     no 1.5-round tail (R15 wasted ~25% in a half-empty second round).
//   - __launch_bounds__(512,4) caps VGPR at 128 (acc 64 + frags 32 + addr
//     ~20) so 2 blocks/CU is achievable; 32-bit element offsets for staging.
//   - counted vmcnt kept: main-loop wait vmcnt(3) = "tile t+1 landed,
//     t+2's 3 loads stay in flight across the barrier". Never drains to 0
//     except the final tail tile.
// attn: frozen at R12 (92.9us, MfmaUtil 30.8, conflicts 0).

#define TT 2048
#define CC 1024
#define HH 16
#define DD 64
#define BB 4

typedef unsigned short u16;
typedef unsigned int u32;
typedef __attribute__((ext_vector_type(8))) short bf16x8;
typedef __attribute__((ext_vector_type(4))) float f32x4;
typedef __attribute__((ext_vector_type(4))) u32 u32x4;

#if __has_builtin(__builtin_amdgcn_exp2f)
#define EXP2(x) __builtin_amdgcn_exp2f(x)
#else
#define EXP2(x) __expf((x) * 0.6931471805599453f)
#endif

__device__ __forceinline__ u16 f2bf(float f) {
    u32 u = __builtin_bit_cast(u32, f);
    u += 0x7FFFu + ((u >> 16) & 1u);
    return (u16)(u >> 16);
}
__device__ __forceinline__ u32 pk2(float a, float b) {
    u32 ua = __builtin_bit_cast(u32, a); ua += 0x7FFFu + ((ua >> 16) & 1u);
    u32 ub = __builtin_bit_cast(u32, b); ub += 0x7FFFu + ((ub >> 16) & 1u);
    return __builtin_amdgcn_perm(ub, ua, 0x07060302);  // {hi16(ub), hi16(ua)}
}
__device__ __forceinline__ u32 cvtpk(float lo, float hi) {
    u32 r;
    asm("v_cvt_pk_bf16_f32 %0, %1, %2" : "=v"(r) : "v"(lo), "v"(hi));
    return r;
}

#define GLDS(g, l) __builtin_amdgcn_global_load_lds( \
    (const __attribute__((address_space(1))) void*)(g), \
    (__attribute__((address_space(3))) void*)(l), 16, 0, 0)

// ---------------------------------------------------------------------------
__global__ __launch_bounds__(256) void wcvt(const float* __restrict__ s,
                                            u16* __restrict__ d, int n8) {
    const int i = blockIdx.x * 256 + threadIdx.x;
    if (i < n8) {
        const float4 f0 = ((const float4*)s)[2 * i];
        const float4 f1 = ((const float4*)s)[2 * i + 1];
        uint4 w;
        w.x = pk2(f0.x, f0.y); w.y = pk2(f0.z, f0.w);
        w.z = pk2(f1.x, f1.y); w.w = pk2(f1.z, f1.w);
        ((uint4*)d)[i] = w;
    }
}

// Fused f32->bf16: x (4096 blocks) + Wq/Wk/Wv (3x512 blocks).
__global__ __launch_bounds__(256) void wcvtA(const float* __restrict__ x,
                                             const float* __restrict__ Wq,
                                             const float* __restrict__ Wk,
                                             const float* __restrict__ Wv,
                                             u16* __restrict__ xb,
                                             u16* __restrict__ Wq16,
                                             u16* __restrict__ Wk16,
                                             u16* __restrict__ Wv16) {
    const int bid = blockIdx.x;
    const float* s; u16* d; int i;
    if (bid < 4096) {
        s = x; d = xb; i = bid * 256 + threadIdx.x;
    } else {
        const int t = bid - 4096;
        const int which = t >> 9, sub = t & 511;
        s = (which == 0) ? Wq : (which == 1) ? Wk : Wv;
        d = (which == 0) ? Wq16 : (which == 1) ? Wk16 : Wv16;
        i = sub * 256 + threadIdx.x;
    }
    const float4 f0 = ((const float4*)s)[2 * i];
    const float4 f1 = ((const float4*)s)[2 * i + 1];
    uint4 w;
    w.x = pk2(f0.x, f0.y); w.y = pk2(f0.z, f0.w);
    w.z = pk2(f1.x, f1.y); w.w = pk2(f1.z, f1.w);
    ((uint4*)d)[i] = w;
}

// ---------------------------------------------------------------------------
// Pipelined GEMM: out = A[8192,1024] @ W[N,1024]^T + bias.
// 256 x BN tile, BK=32, 8 waves, THREE LDS buffers, stage lead 2, counted
// vmcnt (T4): main-loop wait vmcnt(SPT) = "tile t+1 landed, t+2 in flight".
// 72KB LDS at BN=128 -> 2 blocks/CU (TLP across barriers).
// MODE 0: QKV fused (bf16: Q rowmajor | K rowmajor | V^T [B,H,D,T]).
// MODE 1: proj (f32 out + bias).
// ---------------------------------------------------------------------------
template <int BN, int WM, int WN, int MODE>
__global__ __launch_bounds__(512, 4) void gemmT(const u16* __restrict__ Ag,
                                                const u16* __restrict__ Bg,
                                                const float* __restrict__ b0,
                                                const float* __restrict__ b1,
                                                const float* __restrict__ b2,
                                                u16* __restrict__ outQ,
                                                u16* __restrict__ outK,
                                                u16* __restrict__ outV,
                                                float* __restrict__ outF) {
    constexpr int NI = WM / 16, NJ = WN / 16;
    constexpr int WAVES_N = BN / WN;
    constexpr int BUFSZ = (256 + BN) * 32;        // elems per buffer
    constexpr int SPT = 2 + BN / 128;             // GLDS per thread per tile
    constexpr int NT = CC / 32;                   // 32 K-tiles

    extern __shared__ u16 lds[];                  // 3 * BUFSZ elems
    const int tid  = threadIdx.x;
    const int wave = tid >> 6, lane = tid & 63;
    const int quad = lane >> 4, l16 = lane & 15;
    const int wr = wave / WAVES_N, wc = wave & (WAVES_N - 1);

    // bijective XCD chunk swizzle (grid size % 8 == 0 in both modes)
    constexpr int NBX = (MODE == 0 ? 3072 : 1024) / BN;
    const int bid0 = blockIdx.y * NBX + blockIdx.x;
    const int chunk = (NBX * 32) >> 3;
    const int bid  = (bid0 & 7) * chunk + (bid0 >> 3);
    const int bn = (bid % NBX) * BN, bm = (bid / NBX) * 256;

    // ---- thread-constant staging geometry: slot c -> row=c>>2, pos=c&3,
    // fetch global chunk kc = pos ^ sigma(row), sigma(row)=(row>>1)&3 ----
    u32 aOff[2]; int aDst[2];
#pragma unroll
    for (int g = 0; g < 2; g++) {
        const int c = g * 512 + tid;
        const int row = c >> 2;
        const int kc = (c & 3) ^ ((row >> 1) & 3);
        aOff[g] = (u32)(bm + row) * CC + kc * 8;
        aDst[g] = c * 8;
    }
    u32 bOff[BN / 128]; int bDst[BN / 128];
#pragma unroll
    for (int g = 0; g < BN / 128; g++) {
        const int c = g * 512 + tid;
        const int row = c >> 2;
        const int kc = (c & 3) ^ ((row >> 1) & 3);
        bOff[g] = (u32)(bn + row) * CC + kc * 8;
        bDst[g] = 8192 + c * 8;
    }

    // ---- thread-constant fragment-read offsets (elems) ----
    int aRd[NI], bRd[NJ];
#pragma unroll
    for (int i = 0; i < NI; i++) {
        const int row = wr * WM + i * 16 + l16;
        const int p = quad ^ ((row >> 1) & 3);
        aRd[i] = row * 32 + p * 8;
    }
#pragma unroll
    for (int j = 0; j < NJ; j++) {
        const int row = wc * WN + j * 16 + l16;
        const int p = quad ^ ((row >> 1) & 3);
        bRd[j] = 8192 + row * 32 + p * 8;
    }

    f32x4 acc[NI][NJ] = {};

#define STAGE_T(t)                                                        \
    {                                                                     \
        u16* dst = &lds[((t) % 3) * BUFSZ];                               \
        const int k0 = (t) * 32;                                          \
        _Pragma("unroll")                                                 \
        for (int g = 0; g < 2; g++)                                       \
            GLDS(&Ag[(size_t)aOff[g] + k0], &dst[aDst[g]]);               \
        _Pragma("unroll")                                                 \
        for (int g = 0; g < BN / 128; g++)                                \
            GLDS(&Bg[(size_t)bOff[g] + k0], &dst[bDst[g]]);               \
    }

#define COMPUTE_T(t)                                                      \
    {                                                                     \
        const u16* buf = &lds[((t) % 3) * BUFSZ];                         \
        bf16x8 af[NI], bfr[NJ];                                           \
        _Pragma("unroll")                                                 \
        for (int i = 0; i < NI; i++) af[i] = *(const bf16x8*)&buf[aRd[i]];\
        _Pragma("unroll")                                                 \
        for (int j = 0; j < NJ; j++) bfr[j] = *(const bf16x8*)&buf[bRd[j]];\
        __builtin_amdgcn_s_setprio(1);                                    \
        _Pragma("unroll")                                                 \
        for (int i = 0; i < NI; i++)                                      \
            _Pragma("unroll")                                             \
            for (int j = 0; j < NJ; j++)                                  \
                acc[i][j] = __builtin_amdgcn_mfma_f32_16x16x32_bf16(      \
                    af[i], bfr[j], acc[i][j], 0, 0, 0);                   \
        __builtin_amdgcn_s_setprio(0);                                    \
    }

#define WAIT_MAIN()                                                       \
    if constexpr (SPT == 3) asm volatile("s_waitcnt vmcnt(3)" ::: "memory"); \
    else                    asm volatile("s_waitcnt vmcnt(4)" ::: "memory");

    // prologue: stage tiles 0,1; wait tile0 (tile1 stays in flight)
    STAGE_T(0); STAGE_T(1);
    WAIT_MAIN();
    __builtin_amdgcn_sched_barrier(0);
    __builtin_amdgcn_s_barrier();
    __builtin_amdgcn_sched_barrier(0);

#pragma unroll 1
    for (int t = 0; t < NT - 2; t++) {
        STAGE_T(t + 2);
        COMPUTE_T(t);
        WAIT_MAIN();
        __builtin_amdgcn_sched_barrier(0);
        __builtin_amdgcn_s_barrier();
        __builtin_amdgcn_sched_barrier(0);
    }
    // tail: tiles NT-2 (landed), NT-1 (drain then compute)
    COMPUTE_T(NT - 2);
    asm volatile("s_waitcnt vmcnt(0)" ::: "memory");
    __builtin_amdgcn_sched_barrier(0);
    __builtin_amdgcn_s_barrier();
    __builtin_amdgcn_sched_barrier(0);
    COMPUTE_T(NT - 1);

#undef STAGE_T
#undef COMPUTE_T
#undef WAIT_MAIN

    // ---- epilogue ----
    if (MODE == 1) {
#pragma unroll
        for (int j = 0; j < NJ; j++) {
            const int col = bn + wc * WN + j * 16 + l16;
            const float bv = b0[col];
#pragma unroll
            for (int i = 0; i < NI; i++) {
                const int row0 = bm + wr * WM + i * 16 + quad * 4;
#pragma unroll
                for (int r = 0; r < 4; r++)
                    outF[(size_t)(row0 + r) * CC + col] = acc[i][j][r] + bv;
            }
        }
    } else {
        const int mid = bn >> 10;   // 0=Q,1=K,2=V (block-uniform; BN | 1024)
        const float* bias = (mid == 0) ? b0 : (mid == 1) ? b1 : b2;
#pragma unroll
        for (int j = 0; j < NJ; j++) {
            const int col  = bn + wc * WN + j * 16 + l16;
            const int colL = col & (CC - 1);
            const float bv = bias[colL];
#pragma unroll
            for (int i = 0; i < NI; i++) {
                const int row0 = bm + wr * WM + i * 16 + quad * 4;
                if (mid < 2) {
                    u16* out = mid ? outK : outQ;
#pragma unroll
                    for (int r = 0; r < 4; r++)
                        out[(size_t)(row0 + r) * CC + colL] = f2bf(acc[i][j][r] + bv);
                } else {
                    const int hh = colL >> 6, dch = colL & 63;
                    const int bb = row0 >> 11, t0 = row0 & (TT - 1);
                    const size_t idx = (((size_t)bb * HH + hh) * DD + dch) * TT + t0;
                    uint2 w;
                    w.x = pk2(acc[i][j][0] + bv, acc[i][j][1] + bv);
                    w.y = pk2(acc[i][j][2] + bv, acc[i][j][3] + bv);
                    *(uint2*)&outV[idx] = w;
                }
            }
        }
    }
}

// ---------------------------------------------------------------------------
// Flash attention (frozen since R12). Block = (qt,h,b): 256 q-rows,
// 8 waves x 32 rows. Swapped QK^T, in-register P, ks-split softmax/PV,
// double-buffered GLDS, single raw barrier per tile.
// ---------------------------------------------------------------------------
__global__ __launch_bounds__(512) void attn(const u16* __restrict__ Q,
                                            const u16* __restrict__ Kb,
                                            const u16* __restrict__ Vt,
                                            const int* __restrict__ mask,
                                            u16* __restrict__ Y) {
    const int b = blockIdx.z, h = blockIdx.y, qt = blockIdx.x;
    const int tid  = threadIdx.x;
    const int wave = tid >> 6, lane = tid & 63;
    const int quad = lane >> 4, l16 = lane & 15;
    const int qrow0 = qt * 256 + wave * 32;

    __shared__ u16 Ks[2][64 * 64];              // [key][dim]
    __shared__ u16 Vs[2][64 * 64];              // [d][key]
    __shared__ __align__(16) float bias_lds[TT];  // 0 or -1e38 per key

    const size_t qb = ((size_t)b * TT + qrow0) * CC + h * DD;

    bf16x8 qf[2][2];
#pragma unroll
    for (int m = 0; m < 2; m++)
#pragma unroll
        for (int ks = 0; ks < 2; ks++)
            qf[m][ks] = *(const bf16x8*)&Q[qb + (size_t)(m * 16 + l16) * CC + ks * 32 + quad * 8];

    {
        const int i = tid * 4;
        const int4 m0 = *(const int4*)&mask[b * TT + i];
        bias_lds[i + 0] = m0.x ? 0.f : -1e38f;
        bias_lds[i + 1] = m0.y ? 0.f : -1e38f;
        bias_lds[i + 2] = m0.z ? 0.f : -1e38f;
        bias_lds[i + 3] = m0.w ? 0.f : -1e38f;
    }

    const int c0 = tid;
    const int r0 = c0 >> 3;
    const int kp0 = (c0 & 7) ^ ((((r0 >> 3) & 1) << 2) | (r0 & 3));
    const int vp0 = (c0 & 7) ^ (r0 & 7);
    const u16* kgp = Kb + ((size_t)b * TT) * CC + h * DD;
    const u16* vgp = Vt + ((size_t)(b * HH + h) * DD) * TT;

    const int rowA = ((l16 >> 2) << 3) | (l16 & 3);
    const int s0k  = (((l16 >> 2) & 1) << 2) | (l16 & 3);

    f32x4 o[2][4] = {};
    float lsum[2] = {};
    const float SC = 0.18033688011112042f;   // 0.125 * log2(e)

    GLDS(&kgp[(size_t)r0 * CC + kp0 * 8], &Ks[0][c0 * 8]);
    GLDS(&vgp[(size_t)r0 * TT + vp0 * 8], &Vs[0][c0 * 8]);
    asm volatile("s_waitcnt vmcnt(0) lgkmcnt(0)" ::: "memory");
    __builtin_amdgcn_s_barrier();
    __builtin_amdgcn_sched_barrier(0);

#pragma unroll 1
    for (int kt = 0; kt < TT; kt += 64) {
        const int cur = (kt >> 6) & 1;
        const u16* Kc = &Ks[cur][0];
        const u16* Vc = &Vs[cur][0];

        if (kt + 64 < TT) {
            const int nxt = cur ^ 1;
            GLDS(&kgp[(size_t)(kt + 64 + r0) * CC + kp0 * 8], &Ks[nxt][c0 * 8]);
            GLDS(&vgp[(size_t)r0 * TT + kt + 64 + vp0 * 8], &Vs[nxt][c0 * 8]);
        }

        const f32x4 bA = *(const f32x4*)&bias_lds[kt + quad * 8];
        const f32x4 bB = *(const f32x4*)&bias_lds[kt + quad * 8 + 4];
        const f32x4 bC = *(const f32x4*)&bias_lds[kt + 32 + quad * 8];
        const f32x4 bD = *(const f32x4*)&bias_lds[kt + 32 + quad * 8 + 4];

        f32x4 s2[2][4] = {};
        __builtin_amdgcn_s_setprio(1);
#pragma unroll
        for (int n = 0; n < 4; n++) {
            const int rowK = rowA + (n & 1) * 4 + (n >> 1) * 32;
#pragma unroll
            for (int ks = 0; ks < 2; ks++) {
                const int pos = ((ks << 2) + quad) ^ s0k;
                const bf16x8 kf = *(const bf16x8*)&Kc[rowK * 64 + pos * 8];
#pragma unroll
                for (int m = 0; m < 2; m++)
                    s2[m][n] = __builtin_amdgcn_mfma_f32_16x16x32_bf16(kf, qf[m][ks], s2[m][n], 0, 0, 0);
            }
        }
        __builtin_amdgcn_s_setprio(0);

#pragma unroll
        for (int ks = 0; ks < 2; ks++) {
            bf16x8 pf[2];
#pragma unroll
            for (int m = 0; m < 2; m++) {
                u32 pw[4];
#pragma unroll
                for (int nn = 0; nn < 2; nn++) {
                    const int n = 2 * ks + nn;
                    const f32x4 bv = (n == 0) ? bA : (n == 1) ? bB : (n == 2) ? bC : bD;
                    const float p0 = EXP2(fmaf(s2[m][n][0], SC, bv[0]));
                    const float p1 = EXP2(fmaf(s2[m][n][1], SC, bv[1]));
                    const float p2 = EXP2(fmaf(s2[m][n][2], SC, bv[2]));
                    const float p3 = EXP2(fmaf(s2[m][n][3], SC, bv[3]));
                    lsum[m] += (p0 + p1) + (p2 + p3);
                    pw[2 * nn]     = cvtpk(p0, p1);
                    pw[2 * nn + 1] = cvtpk(p2, p3);
                }
                const u32x4 t = { pw[0], pw[1], pw[2], pw[3] };
                pf[m] = __builtin_bit_cast(bf16x8, t);
            }
            __builtin_amdgcn_s_setprio(1);
#pragma unroll
            for (int dt = 0; dt < 4; dt++) {
                const int vrow = dt * 16 + l16;
                const int pos = ((ks << 2) + quad) ^ (vrow & 7);
                const bf16x8 vf = *(const bf16x8*)&Vc[vrow * 64 + pos * 8];
#pragma unroll
                for (int m = 0; m < 2; m++)
                    o[m][dt] = __builtin_amdgcn_mfma_f32_16x16x32_bf16(pf[m], vf, o[m][dt], 0, 0, 0);
            }
            __builtin_amdgcn_s_setprio(0);
        }

        asm volatile("s_waitcnt vmcnt(0)" ::: "memory");
        __builtin_amdgcn_sched_barrier(0);
        __builtin_amdgcn_s_barrier();
    }

#pragma unroll
    for (int m = 0; m < 2; m++) {
        lsum[m] += __shfl_xor(lsum[m], 16, 64);
        lsum[m] += __shfl_xor(lsum[m], 32, 64);
    }

#pragma unroll
    for (int m = 0; m < 2; m++) {
        float inv[4];
#pragma unroll
        for (int r = 0; r < 4; r++)
            inv[r] = 1.0f / __shfl(lsum[m], quad * 4 + r, 64);
#pragma unroll
        for (int dt = 0; dt < 4; dt++)
#pragma unroll
            for (int r = 0; r < 4; r++)
                Y[qb + (size_t)(m * 16 + quad * 4 + r) * CC + dt * 16 + l16] = f2bf(o[m][dt][r] * inv[r]);
    }
}

// ---------------------------------------------------------------------------
extern "C" void kernel_launch(void* const* d_in, const int* in_sizes, int n_in,
                              void* d_out, int out_size, void* d_ws, size_t ws_size,
                              hipStream_t stream) {
    const float* x    = (const float*)d_in[0];
    const int*   mask = (const int*)d_in[1];
    const float* Wq   = (const float*)d_in[2];
    const float* bq   = (const float*)d_in[3];
    const float* Wk   = (const float*)d_in[4];
    const float* bk   = (const float*)d_in[5];
    const float* Wv   = (const float*)d_in[6];
    const float* bv   = (const float*)d_in[7];
    const float* Wp   = (const float*)d_in[8];
    const float* bp   = (const float*)d_in[9];

    u16* ws = (u16*)d_ws;
    const size_t sz = (size_t)BB * TT * CC;     // 8,388,608 elems
    u16* Qb   = ws;              // Q; attn writes O here
    u16* Kbuf = ws + sz;         // K; reused for bf16 Wp after attn
    u16* Vtb  = ws + 2 * sz;     // V^T [B,H,D,T]   (ws total 48 MiB)

    u16* xb   = (u16*)d_out;     // squatters in d_out (dead by proj GEMM)
    u16* Wq16 = xb + sz;
    u16* Wk16 = Wq16 + (size_t)CC * CC;
    u16* Wv16 = Wk16 + (size_t)CC * CC;   // Wq16..Wv16 contiguous = W[3072][1024]

    static bool inited = false;
    if (!inited) {
        (void)hipFuncSetAttribute((const void*)gemmT<128, 64, 64, 0>,
                                  hipFuncAttributeMaxDynamicSharedMemorySize, 73728);
        (void)hipFuncSetAttribute((const void*)gemmT<128, 64, 64, 1>,
                                  hipFuncAttributeMaxDynamicSharedMemorySize, 73728);
        inited = true;
    }

    const int W8 = CC * CC / 8;      // 131072

    wcvtA<<<5632, 256, 0, stream>>>(x, Wq, Wk, Wv, xb, Wq16, Wk16, Wv16);

    gemmT<128, 64, 64, 0><<<dim3(24, 32), 512, 73728, stream>>>(
        xb, Wq16, bq, bk, bv, Qb, Kbuf, Vtb, nullptr);

    attn<<<dim3(TT / 256, HH, BB), 512, 0, stream>>>(Qb, Kbuf, Vtb, mask, Qb);

    wcvt<<<512, 256, 0, stream>>>(Wp, Kbuf, W8);   // Kbuf dead after attn

    gemmT<128, 64, 64, 1><<<dim3(8, 32), 512, 73728, stream>>>(
        Qb, Kbuf, bp, nullptr, nullptr, nullptr, nullptr, nullptr, (float*)d_out);
}